// Round 12
// baseline (815.592 us; speedup 1.0000x reference)
//
#include <hip/hip_runtime.h>
#include <hip/hip_bf16.h>
#include <hip/hip_fp16.h>
#include <math.h>

#define NN 100000
#define EE 1600000
#define ET 1700000   // E + N self-loops
#define HID 32

#define BKT_SHIFT 10
#define BKT_MASK 1023
#define NBKT 98            // ceil(NN / 1024)
#define CAP 18944          // padded bucket capacity (mean 17347 + ~12 sigma)
#define EPB 4096           // edges per block in stage A
#define NBLK_A 416         // ceil(ET / EPB)

// ---- seed bucket bases + zero degree histogram ----
__global__ __launch_bounds__(128) void k_seed(int* __restrict__ bucket_fill, int* __restrict__ dcnt) {
    int t = threadIdx.x;
    if (t < NBKT) bucket_fill[t] = t * CAP;
    if (t < 64) dcnt[t] = 0;
}

// ---- stage A: scatter (src,dst) pairs into padded bucket regions (block-chunk reserved) ----
__global__ __launch_bounds__(256) void k_bkt_scatter(const int* __restrict__ src32, const int* __restrict__ dst32,
                                                     int* __restrict__ bucket_fill, int2* __restrict__ pairs) {
    __shared__ int h[NBKT];
    __shared__ int bbase[NBKT];
    for (int i = threadIdx.x; i < NBKT; i += 256) h[i] = 0;
    __syncthreads();
    int base = blockIdx.x * EPB;
    for (int k = 0; k < EPB; k += 256) {
        int t = base + k + threadIdx.x;
        if (t < ET) atomicAdd(&h[dst32[t] >> BKT_SHIFT], 1);
    }
    __syncthreads();
    for (int i = threadIdx.x; i < NBKT; i += 256) {
        int c = h[i];
        bbase[i] = c ? atomicAdd(&bucket_fill[i], c) : 0;
        h[i] = 0;  // becomes local fill counter (same thread owns bin -> no race)
    }
    __syncthreads();
    for (int k = 0; k < EPB; k += 256) {
        int t = base + k + threadIdx.x;
        if (t < ET) {
            int sv = src32[t], dv = dst32[t];
            int b = dv >> BKT_SHIFT;
            int off = atomicAdd(&h[b], 1);
            pairs[bbase[b] + off] = make_int2(sv, dv);
        }
    }
}

// ---- stage B: per-bucket fine CSR (1024 nodes in LDS) + in-bucket scatter of src ----
__global__ __launch_bounds__(512) void k_bkt_csr(const int2* __restrict__ pairs, const int* __restrict__ bucket_fill,
                                                 int* __restrict__ rowptr, int* __restrict__ rowend,
                                                 int* __restrict__ deg, int* __restrict__ src_sorted) {
    __shared__ int h[1024];
    __shared__ int tmp[512];
    int t = threadIdx.x;
    int b = blockIdx.x;
    int e0 = b * CAP, e1 = bucket_fill[b];
    int node0 = b << BKT_SHIFT;

    h[t] = 0;
    h[t + 512] = 0;
    __syncthreads();
    for (int e = e0 + t; e < e1; e += 512) atomicAdd(&h[pairs[e].y & BKT_MASK], 1);
    __syncthreads();

    int i0 = 2 * t, i1 = 2 * t + 1;
    int v0 = h[i0], v1 = h[i1];
    int s = v0 + v1;
    tmp[t] = s;
    for (int off = 1; off < 512; off <<= 1) {
        __syncthreads();
        int u = (t >= off) ? tmp[t - off] : 0;
        __syncthreads();
        tmp[t] += u;
    }
    __syncthreads();
    int excl = tmp[t] - s;
    h[i0] = excl;
    h[i1] = excl + v0;
    __syncthreads();

    int n0 = node0 + i0, n1 = node0 + i1;
    if (n0 < NN) { rowptr[n0] = e0 + excl;      rowend[n0] = e0 + excl + v0;      deg[n0] = v0; }
    if (n1 < NN) { rowptr[n1] = e0 + excl + v0; rowend[n1] = e0 + excl + v0 + v1; deg[n1] = v1; }
    __syncthreads();

    for (int e = e0 + t; e < e1; e += 512) {
        int2 p = pairs[e];
        int sl = atomicAdd(&h[p.y & BKT_MASK], 1);
        src_sorted[e0 + sl] = p.x;
    }
}

// ---- degree counting sort: histogram / scan / fill ----
__global__ __launch_bounds__(256) void k_dhist(const int* __restrict__ deg, int* __restrict__ dcnt) {
    int t = blockIdx.x * 256 + threadIdx.x;
    if (t < NN) atomicAdd(&dcnt[min(deg[t], 63)], 1);
}

__global__ __launch_bounds__(64) void k_dscan(const int* __restrict__ dcnt, int* __restrict__ dfill) {
    int t = threadIdx.x;  // 64 threads, one wave
    int c = dcnt[t];
    int v = c;
    for (int off = 1; off < 64; off <<= 1) {
        int u = __shfl_up(v, off, 64);
        if (t >= off) v += u;
    }
    dfill[t] = v - c;  // exclusive
}

__global__ __launch_bounds__(256) void k_dfill(const int* __restrict__ deg, int* __restrict__ dfill,
                                               int* __restrict__ order) {
    int t = blockIdx.x * 256 + threadIdx.x;
    if (t < NN) {
        int slot = atomicAdd(&dfill[min(deg[t], 63)], 1);
        order[slot] = t;
    }
}

// ---- helpers ----
__device__ __forceinline__ void acc8(uint4 r, float* c) {
    float2 f0 = __half22float2(*reinterpret_cast<__half2*>(&r.x));
    float2 f1 = __half22float2(*reinterpret_cast<__half2*>(&r.y));
    float2 f2 = __half22float2(*reinterpret_cast<__half2*>(&r.z));
    float2 f3 = __half22float2(*reinterpret_cast<__half2*>(&r.w));
    c[0] += f0.x; c[1] += f0.y; c[2] += f1.x; c[3] += f1.y;
    c[4] += f2.x; c[5] += f2.y; c[6] += f3.x; c[7] += f3.y;
}

// ---- layer 1 fused: thread-per-node (degree-sorted) pull-agg + 1->32 linear + relu ----
__global__ __launch_bounds__(256) void k_pull1(const int* __restrict__ order,
                                               const int* __restrict__ rowptr, const int* __restrict__ rowend,
                                               const int* __restrict__ src_sorted,
                                               const float* __restrict__ x0, const float* __restrict__ W1,
                                               const float* __restrict__ b1, __half* __restrict__ hout) {
    __shared__ float W1l[32], b1l[32];
    if (threadIdx.x < 32) {
        W1l[threadIdx.x] = W1[threadIdx.x];
        b1l[threadIdx.x] = b1[threadIdx.x];
    }
    __syncthreads();
    int gid = blockIdx.x * 256 + threadIdx.x;
    if (gid >= NN) return;
    int g = order[gid];
    int e0 = rowptr[g], e1 = rowend[g];
    float a0 = x0[g], a1 = 0.f, a2 = 0.f, a3 = 0.f, a4 = 0.f, a5 = 0.f, a6 = 0.f, a7 = 0.f;
    int e = e0;
    for (; e + 8 <= e1; e += 8) {
        a0 += x0[src_sorted[e + 0]];
        a1 += x0[src_sorted[e + 1]];
        a2 += x0[src_sorted[e + 2]];
        a3 += x0[src_sorted[e + 3]];
        a4 += x0[src_sorted[e + 4]];
        a5 += x0[src_sorted[e + 5]];
        a6 += x0[src_sorted[e + 6]];
        a7 += x0[src_sorted[e + 7]];
    }
    for (; e < e1; ++e) a0 += x0[src_sorted[e]];
    float s = ((a0 + a1) + (a2 + a3)) + ((a4 + a5) + (a6 + a7));

    uint4* orow = reinterpret_cast<uint4*>(hout) + ((size_t)g << 2);
#pragma unroll
    for (int q = 0; q < 4; ++q) {
        float o0 = fmaxf(fmaf(s, W1l[8 * q + 0], b1l[8 * q + 0]), 0.f);
        float o1 = fmaxf(fmaf(s, W1l[8 * q + 1], b1l[8 * q + 1]), 0.f);
        float o2 = fmaxf(fmaf(s, W1l[8 * q + 2], b1l[8 * q + 2]), 0.f);
        float o3 = fmaxf(fmaf(s, W1l[8 * q + 3], b1l[8 * q + 3]), 0.f);
        float o4 = fmaxf(fmaf(s, W1l[8 * q + 4], b1l[8 * q + 4]), 0.f);
        float o5 = fmaxf(fmaf(s, W1l[8 * q + 5], b1l[8 * q + 5]), 0.f);
        float o6 = fmaxf(fmaf(s, W1l[8 * q + 6], b1l[8 * q + 6]), 0.f);
        float o7 = fmaxf(fmaf(s, W1l[8 * q + 7], b1l[8 * q + 7]), 0.f);
        __half2 p0 = __floats2half2_rn(o0, o1);
        __half2 p1 = __floats2half2_rn(o2, o3);
        __half2 p2 = __floats2half2_rn(o4, o5);
        __half2 p3 = __floats2half2_rn(o6, o7);
        orow[q] = make_uint4(*reinterpret_cast<unsigned*>(&p0), *reinterpret_cast<unsigned*>(&p1),
                             *reinterpret_cast<unsigned*>(&p2), *reinterpret_cast<unsigned*>(&p3));
    }
}

// ---- fused pull-agg + 32x32 matmul (+relu), 4 lanes/node (degree-sorted), uint4 gathers ----
template <int RELU>
__global__ __launch_bounds__(256) void k_agg_mm(const int* __restrict__ order,
                                                const int* __restrict__ rowptr, const int* __restrict__ rowend,
                                                const int* __restrict__ src_sorted,
                                                const __half* __restrict__ hin, const float* __restrict__ W,
                                                const float* __restrict__ b, __half* __restrict__ hout) {
    __shared__ float Wl[1024];
    for (int i = threadIdx.x; i < 1024; i += 256) Wl[i] = W[i];
    __syncthreads();
    int gid = (blockIdx.x * 256 + threadIdx.x) >> 2;   // 64 nodes/block
    if (gid >= NN) return;
    int g = order[gid];
    int j = threadIdx.x & 3;
    const uint4* tab = reinterpret_cast<const uint4*>(hin);
    int e0 = rowptr[g], e1 = rowend[g];
    float x[8], y[8];
#pragma unroll
    for (int i = 0; i < 8; ++i) { x[i] = 0.f; y[i] = 0.f; }
    acc8(tab[(g << 2) + j], x);  // self term
    int e = e0;
    for (; e + 8 <= e1; e += 8) {
        int s0 = src_sorted[e + 0], s1 = src_sorted[e + 1], s2 = src_sorted[e + 2], s3 = src_sorted[e + 3];
        int s4 = src_sorted[e + 4], s5 = src_sorted[e + 5], s6 = src_sorted[e + 6], s7 = src_sorted[e + 7];
        uint4 r0 = tab[(s0 << 2) + j];
        uint4 r1 = tab[(s1 << 2) + j];
        uint4 r2 = tab[(s2 << 2) + j];
        uint4 r3 = tab[(s3 << 2) + j];
        uint4 r4 = tab[(s4 << 2) + j];
        uint4 r5 = tab[(s5 << 2) + j];
        uint4 r6 = tab[(s6 << 2) + j];
        uint4 r7 = tab[(s7 << 2) + j];
        acc8(r0, x); acc8(r1, y); acc8(r2, x); acc8(r3, y);
        acc8(r4, x); acc8(r5, y); acc8(r6, x); acc8(r7, y);
    }
    for (; e < e1; ++e) acc8(tab[(src_sorted[e] << 2) + j], x);
#pragma unroll
    for (int i = 0; i < 8; ++i) x[i] += y[i];

    float o[8];
#pragma unroll
    for (int i = 0; i < 8; ++i) o[i] = b[8 * j + i];
#pragma unroll
    for (int sl = 0; sl < 4; ++sl) {
#pragma unroll
        for (int r = 0; r < 8; ++r) {
            float xk = __shfl(x[r], sl, 4);
            int k = 8 * sl + r;
            float4 w0 = *reinterpret_cast<const float4*>(&Wl[k * 32 + 8 * j]);
            float4 w1 = *reinterpret_cast<const float4*>(&Wl[k * 32 + 8 * j + 4]);
            o[0] = fmaf(xk, w0.x, o[0]); o[1] = fmaf(xk, w0.y, o[1]);
            o[2] = fmaf(xk, w0.z, o[2]); o[3] = fmaf(xk, w0.w, o[3]);
            o[4] = fmaf(xk, w1.x, o[4]); o[5] = fmaf(xk, w1.y, o[5]);
            o[6] = fmaf(xk, w1.z, o[6]); o[7] = fmaf(xk, w1.w, o[7]);
        }
    }
    if (RELU) {
#pragma unroll
        for (int i = 0; i < 8; ++i) o[i] = fmaxf(o[i], 0.f);
    }
    __half2 p0 = __floats2half2_rn(o[0], o[1]);
    __half2 p1 = __floats2half2_rn(o[2], o[3]);
    __half2 p2 = __floats2half2_rn(o[4], o[5]);
    __half2 p3 = __floats2half2_rn(o[6], o[7]);
    uint4 st = make_uint4(*reinterpret_cast<unsigned*>(&p0), *reinterpret_cast<unsigned*>(&p1),
                          *reinterpret_cast<unsigned*>(&p2), *reinterpret_cast<unsigned*>(&p3));
    reinterpret_cast<uint4*>(hout)[(g << 2) + j] = st;
}

// ---- layer 4 fused: pull-agg + W3 matmul + W5 projections -> u16 (b5 folded), v16 ----
__global__ __launch_bounds__(256) void k_agg_mm_proj(const int* __restrict__ order,
                                                     const int* __restrict__ rowptr, const int* __restrict__ rowend,
                                                     const int* __restrict__ src_sorted,
                                                     const __half* __restrict__ hin, const float* __restrict__ W3,
                                                     const float* __restrict__ b3,
                                                     const float* __restrict__ W5, const float* __restrict__ b5,
                                                     __half* __restrict__ u16, __half* __restrict__ v16) {
    __shared__ float W3l[1024];
    __shared__ float W5l[2048];
    for (int i = threadIdx.x; i < 1024; i += 256) W3l[i] = W3[i];
    for (int i = threadIdx.x; i < 2048; i += 256) W5l[i] = W5[i];
    __syncthreads();
    int gid = (blockIdx.x * 256 + threadIdx.x) >> 2;
    if (gid >= NN) return;
    int g = order[gid];
    int j = threadIdx.x & 3;
    const uint4* tab = reinterpret_cast<const uint4*>(hin);
    int e0 = rowptr[g], e1 = rowend[g];
    float x[8], y[8];
#pragma unroll
    for (int i = 0; i < 8; ++i) { x[i] = 0.f; y[i] = 0.f; }
    acc8(tab[(g << 2) + j], x);  // self term
    int e = e0;
    for (; e + 8 <= e1; e += 8) {
        int s0 = src_sorted[e + 0], s1 = src_sorted[e + 1], s2 = src_sorted[e + 2], s3 = src_sorted[e + 3];
        int s4 = src_sorted[e + 4], s5 = src_sorted[e + 5], s6 = src_sorted[e + 6], s7 = src_sorted[e + 7];
        uint4 r0 = tab[(s0 << 2) + j];
        uint4 r1 = tab[(s1 << 2) + j];
        uint4 r2 = tab[(s2 << 2) + j];
        uint4 r3 = tab[(s3 << 2) + j];
        uint4 r4 = tab[(s4 << 2) + j];
        uint4 r5 = tab[(s5 << 2) + j];
        uint4 r6 = tab[(s6 << 2) + j];
        uint4 r7 = tab[(s7 << 2) + j];
        acc8(r0, x); acc8(r1, y); acc8(r2, x); acc8(r3, y);
        acc8(r4, x); acc8(r5, y); acc8(r6, x); acc8(r7, y);
    }
    for (; e < e1; ++e) acc8(tab[(src_sorted[e] << 2) + j], x);
#pragma unroll
    for (int i = 0; i < 8; ++i) x[i] += y[i];

    // x4 = agg . W3 + b3 (no relu)
    float o[8];
#pragma unroll
    for (int i = 0; i < 8; ++i) o[i] = b3[8 * j + i];
#pragma unroll
    for (int sl = 0; sl < 4; ++sl) {
#pragma unroll
        for (int r = 0; r < 8; ++r) {
            float xk = __shfl(x[r], sl, 4);
            int k = 8 * sl + r;
            float4 w0 = *reinterpret_cast<const float4*>(&W3l[k * 32 + 8 * j]);
            float4 w1 = *reinterpret_cast<const float4*>(&W3l[k * 32 + 8 * j + 4]);
            o[0] = fmaf(xk, w0.x, o[0]); o[1] = fmaf(xk, w0.y, o[1]);
            o[2] = fmaf(xk, w0.z, o[2]); o[3] = fmaf(xk, w0.w, o[3]);
            o[4] = fmaf(xk, w1.x, o[4]); o[5] = fmaf(xk, w1.y, o[5]);
            o[6] = fmaf(xk, w1.z, o[6]); o[7] = fmaf(xk, w1.w, o[7]);
        }
    }
    // u = x4 . W5[0:32,:] + b5 ; v = x4 . W5[32:64,:]
    float u[8], v[8];
#pragma unroll
    for (int i = 0; i < 8; ++i) { u[i] = b5[8 * j + i]; v[i] = 0.f; }
#pragma unroll
    for (int sl = 0; sl < 4; ++sl) {
#pragma unroll
        for (int r = 0; r < 8; ++r) {
            float xk = __shfl(o[r], sl, 4);
            int k = 8 * sl + r;
            float4 a0 = *reinterpret_cast<const float4*>(&W5l[k * 32 + 8 * j]);
            float4 a1 = *reinterpret_cast<const float4*>(&W5l[k * 32 + 8 * j + 4]);
            u[0] = fmaf(xk, a0.x, u[0]); u[1] = fmaf(xk, a0.y, u[1]);
            u[2] = fmaf(xk, a0.z, u[2]); u[3] = fmaf(xk, a0.w, u[3]);
            u[4] = fmaf(xk, a1.x, u[4]); u[5] = fmaf(xk, a1.y, u[5]);
            u[6] = fmaf(xk, a1.z, u[6]); u[7] = fmaf(xk, a1.w, u[7]);
            float4 c0 = *reinterpret_cast<const float4*>(&W5l[(32 + k) * 32 + 8 * j]);
            float4 c1 = *reinterpret_cast<const float4*>(&W5l[(32 + k) * 32 + 8 * j + 4]);
            v[0] = fmaf(xk, c0.x, v[0]); v[1] = fmaf(xk, c0.y, v[1]);
            v[2] = fmaf(xk, c0.z, v[2]); v[3] = fmaf(xk, c0.w, v[3]);
            v[4] = fmaf(xk, c1.x, v[4]); v[5] = fmaf(xk, c1.y, v[5]);
            v[6] = fmaf(xk, c1.z, v[6]); v[7] = fmaf(xk, c1.w, v[7]);
        }
    }
    __half2 pu0 = __floats2half2_rn(u[0], u[1]);
    __half2 pu1 = __floats2half2_rn(u[2], u[3]);
    __half2 pu2 = __floats2half2_rn(u[4], u[5]);
    __half2 pu3 = __floats2half2_rn(u[6], u[7]);
    uint4 su = make_uint4(*reinterpret_cast<unsigned*>(&pu0), *reinterpret_cast<unsigned*>(&pu1),
                          *reinterpret_cast<unsigned*>(&pu2), *reinterpret_cast<unsigned*>(&pu3));
    reinterpret_cast<uint4*>(u16)[(g << 2) + j] = su;
    __half2 pv0 = __floats2half2_rn(v[0], v[1]);
    __half2 pv1 = __floats2half2_rn(v[2], v[3]);
    __half2 pv2 = __floats2half2_rn(v[4], v[5]);
    __half2 pv3 = __floats2half2_rn(v[6], v[7]);
    uint4 sv = make_uint4(*reinterpret_cast<unsigned*>(&pv0), *reinterpret_cast<unsigned*>(&pv1),
                          *reinterpret_cast<unsigned*>(&pv2), *reinterpret_cast<unsigned*>(&pv3));
    reinterpret_cast<uint4*>(v16)[(g << 2) + j] = sv;
}

// ---- per-edge (2 edges/thread): ALL 16 row-loads hoisted & fenced, then compute ----
__global__ __launch_bounds__(256) void k_edge(const int* __restrict__ src32, const int* __restrict__ dst32,
                                              const __half* __restrict__ u16, const __half* __restrict__ v16,
                                              const float* __restrict__ W6, const float* __restrict__ b6,
                                              float* __restrict__ pd_out, float* __restrict__ partial) {
    int ea = blockIdx.x * 512 + threadIdx.x;   // EE divisible by 512
    int eb = ea + 256;
    int sa = src32[ea], da = dst32[ea];
    int sb = src32[eb], db = dst32[eb];
    const uint4* pua = reinterpret_cast<const uint4*>(u16 + ((size_t)sa << 5));
    const uint4* pva = reinterpret_cast<const uint4*>(v16 + ((size_t)da << 5));
    const uint4* pub = reinterpret_cast<const uint4*>(u16 + ((size_t)sb << 5));
    const uint4* pvb = reinterpret_cast<const uint4*>(v16 + ((size_t)db << 5));

    // hoist all 16 16B gathers into registers; fence so the compiler can't sink them
    uint4 A[4], B[4], C[4], D[4];
#pragma unroll
    for (int q = 0; q < 4; ++q) A[q] = pua[q];
#pragma unroll
    for (int q = 0; q < 4; ++q) B[q] = pva[q];
#pragma unroll
    for (int q = 0; q < 4; ++q) C[q] = pub[q];
#pragma unroll
    for (int q = 0; q < 4; ++q) D[q] = pvb[q];
    __builtin_amdgcn_sched_barrier(0);

    float b60 = b6[0], b61 = b6[1];
    float pda0 = b60, pda1 = b61, pdb0 = b60, pdb1 = b61;
#pragma unroll
    for (int q = 0; q < 4; ++q) {
        const __half2* ah = reinterpret_cast<const __half2*>(&A[q]);
        const __half2* bh = reinterpret_cast<const __half2*>(&B[q]);
        const __half2* ch = reinterpret_cast<const __half2*>(&C[q]);
        const __half2* dh = reinterpret_cast<const __half2*>(&D[q]);
#pragma unroll
        for (int r = 0; r < 4; ++r) {
            float2 fA = __half22float2(__hadd2(ah[r], bh[r]));
            float2 fB = __half22float2(__hadd2(ch[r], dh[r]));
            int jj = q * 8 + 2 * r;
            float w00 = W6[2 * jj + 0], w01 = W6[2 * jj + 1];
            float w10 = W6[2 * (jj + 1) + 0], w11 = W6[2 * (jj + 1) + 1];
            float hA0 = fA.x >= 0.f ? fA.x : 0.1f * fA.x;
            float hA1 = fA.y >= 0.f ? fA.y : 0.1f * fA.y;
            float hB0 = fB.x >= 0.f ? fB.x : 0.1f * fB.x;
            float hB1 = fB.y >= 0.f ? fB.y : 0.1f * fB.y;
            pda0 = fmaf(hA0, w00, pda0); pda1 = fmaf(hA0, w01, pda1);
            pda0 = fmaf(hA1, w10, pda0); pda1 = fmaf(hA1, w11, pda1);
            pdb0 = fmaf(hB0, w00, pdb0); pdb1 = fmaf(hB0, w01, pdb1);
            pdb0 = fmaf(hB1, w10, pdb0); pdb1 = fmaf(hB1, w11, pdb1);
        }
    }
    reinterpret_cast<float2*>(pd_out)[ea] = make_float2(pda0, pda1);
    reinterpret_cast<float2*>(pd_out)[eb] = make_float2(pdb0, pdb1);

    float persA = pda1 - pda0;
    float persB = pdb1 - pdb0;
    const float inv = 3.5355339059327378f;  // 1/(0.2*sqrt(2))
    float cbA[6], cpA[6], cbB[6], cpB[6];
#pragma unroll
    for (int i = 0; i < 6; ++i) {
        float te = 0.2f * (float)i;
        cbA[i] = erff((te - pda0) * inv);
        cpA[i] = erff((te - persA) * inv);
        cbB[i] = erff((te - pdb0) * inv);
        cpB[i] = erff((te - persB) * inv);
    }

    int lane = threadIdx.x & 63;
    int wv = threadIdx.x >> 6;
    __shared__ float sacc[4][25];
#pragma unroll
    for (int i = 0; i < 5; ++i) {
        float pa = 0.25f * persA * (cbA[i + 1] - cbA[i]);
        float pb = 0.25f * persB * (cbB[i + 1] - cbB[i]);
#pragma unroll
        for (int jj = 0; jj < 5; ++jj) {
            float v = pa * (cpA[jj + 1] - cpA[jj]) + pb * (cpB[jj + 1] - cpB[jj]);
            v += __shfl_down(v, 32);
            v += __shfl_down(v, 16);
            v += __shfl_down(v, 8);
            v += __shfl_down(v, 4);
            v += __shfl_down(v, 2);
            v += __shfl_down(v, 1);
            if (lane == 0) sacc[wv][i * 5 + jj] = v;
        }
    }
    __syncthreads();
    if (threadIdx.x < 25) {
        partial[(size_t)blockIdx.x * 25 + threadIdx.x] =
            sacc[0][threadIdx.x] + sacc[1][threadIdx.x] + sacc[2][threadIdx.x] + sacc[3][threadIdx.x];
    }
}

// ---- deterministic final reduction of block partials per bin ----
__global__ __launch_bounds__(256) void k_img(const float* __restrict__ partial, float* __restrict__ img) {
    int bin = blockIdx.x;  // 25 blocks
    float s = 0.f;
    for (int k = threadIdx.x; k < EE / 512; k += 256) s += partial[(size_t)k * 25 + bin];
    s += __shfl_down(s, 32);
    s += __shfl_down(s, 16);
    s += __shfl_down(s, 8);
    s += __shfl_down(s, 4);
    s += __shfl_down(s, 2);
    s += __shfl_down(s, 1);
    __shared__ float wsum[4];
    if ((threadIdx.x & 63) == 0) wsum[threadIdx.x >> 6] = s;
    __syncthreads();
    if (threadIdx.x == 0) img[bin] = wsum[0] + wsum[1] + wsum[2] + wsum[3];
}

extern "C" void kernel_launch(void* const* d_in, const int* in_sizes, int n_in,
                              void* d_out, int out_size, void* d_ws, size_t ws_size,
                              hipStream_t stream) {
    const float* x0 = (const float*)d_in[0];
    // Harness converts integer inputs to int32: edge_index0 is (2, ET) int32.
    const int* src32 = (const int*)d_in[1];
    const int* dst32 = src32 + ET;
    const float* W1 = (const float*)d_in[2];
    const float* b1 = (const float*)d_in[3];
    const float* W2 = (const float*)d_in[4];
    const float* b2 = (const float*)d_in[5];
    const float* W4 = (const float*)d_in[6];
    const float* b4 = (const float*)d_in[7];
    const float* W3 = (const float*)d_in[8];
    const float* b3 = (const float*)d_in[9];
    const float* W5 = (const float*)d_in[10];
    const float* b5 = (const float*)d_in[11];
    const float* W6 = (const float*)d_in[12];
    const float* b6 = (const float*)d_in[13];
    float* out = (float*)d_out;

    const size_t PADDED = (size_t)NBKT * CAP;        // 1,856,512
    char* w = (char*)d_ws;
    int2* pairs = (int2*)w;                          // PADDED int2
    int* src_sorted = (int*)(pairs + PADDED);        // PADDED
    int* bucket_fill = src_sorted + PADDED;          // NBKT
    int* dcnt = bucket_fill + NBKT;                  // 64
    int* dfill = dcnt + 64;                          // 64
    int* rowptr = dfill + 64;                        // NN
    int* rowend = rowptr + NN;                       // NN
    int* deg = rowend + NN;                          // NN
    int* order = deg + NN;                           // NN
    size_t off = ((size_t)((char*)(order + NN) - w) + 63) & ~(size_t)63;
    __half* bufA = (__half*)(w + off);               // NN*32 halfs
    __half* bufB = bufA + (size_t)NN * 32;           // NN*32 halfs
    __half* u16 = bufB + (size_t)NN * 32;            // NN*32 halfs
    __half* v16 = u16 + (size_t)NN * 32;             // NN*32 halfs
    float* partial = (float*)(v16 + (size_t)NN * 32);// (EE/512)*25 floats

    // ---- build CSR via padded-bucket counting sort (no count pass) ----
    k_seed<<<1, 128, 0, stream>>>(bucket_fill, dcnt);
    k_bkt_scatter<<<NBLK_A, 256, 0, stream>>>(src32, dst32, bucket_fill, pairs);
    k_bkt_csr<<<NBKT, 512, 0, stream>>>(pairs, bucket_fill, rowptr, rowend, deg, src_sorted);

    // ---- degree counting sort -> order[] ----
    k_dhist<<<(NN + 255) / 256, 256, 0, stream>>>(deg, dcnt);
    k_dscan<<<1, 64, 0, stream>>>(dcnt, dfill);
    k_dfill<<<(NN + 255) / 256, 256, 0, stream>>>(deg, dfill, order);

    // ---- layer 1 (fused agg + expand, degree-sorted) ----
    k_pull1<<<(NN + 255) / 256, 256, 0, stream>>>(order, rowptr, rowend, src_sorted, x0, W1, b1, bufA);
    // ---- layers 2-3 (4 lanes/node, uint4 gathers, degree-sorted) ----
    k_agg_mm<1><<<(NN * 4 + 255) / 256, 256, 0, stream>>>(order, rowptr, rowend, src_sorted, bufA, W2, b2, bufB);
    k_agg_mm<1><<<(NN * 4 + 255) / 256, 256, 0, stream>>>(order, rowptr, rowend, src_sorted, bufB, W4, b4, bufA);
    // ---- layer 4 + W5 projections ----
    k_agg_mm_proj<<<(NN * 4 + 255) / 256, 256, 0, stream>>>(order, rowptr, rowend, src_sorted, bufA, W3, b3, W5, b5, u16, v16);

    // ---- edge MLP + persistence image (original order) ----
    k_edge<<<EE / 512, 256, 0, stream>>>(src32, dst32, u16, v16, W6, b6, out, partial);
    k_img<<<25, 256, 0, stream>>>(partial, out + 2 * (size_t)EE);
}

// Round 13
// 249.411 us; speedup vs baseline: 3.2701x; 3.2701x over previous
//
#include <hip/hip_runtime.h>
#include <hip/hip_bf16.h>
#include <hip/hip_fp16.h>
#include <math.h>

#define NN 100000
#define EE 1600000
#define ET 1700000   // E + N self-loops
#define HID 32

#define BKT_SHIFT 10
#define BKT_MASK 1023
#define NBKT 98            // ceil(NN / 1024)
#define CAP 18944          // padded bucket capacity (mean 17347 + ~12 sigma)
#define EPB 4096           // edges per block in stage A
#define NBLK_A 416         // ceil(ET / EPB)
#define NBLK_N 391         // ceil(NN / 256)

// ---- seed bucket bases + zero degree histogram ----
__global__ __launch_bounds__(128) void k_seed(int* __restrict__ bucket_fill, int* __restrict__ dcnt) {
    int t = threadIdx.x;
    if (t < NBKT) bucket_fill[t] = t * CAP;
    if (t < 64) dcnt[t] = 0;
}

// ---- stage A: scatter (src,dst) pairs into padded bucket regions (block-chunk reserved) ----
__global__ __launch_bounds__(256) void k_bkt_scatter(const int* __restrict__ src32, const int* __restrict__ dst32,
                                                     int* __restrict__ bucket_fill, int2* __restrict__ pairs) {
    __shared__ int h[NBKT];
    __shared__ int bbase[NBKT];
    for (int i = threadIdx.x; i < NBKT; i += 256) h[i] = 0;
    __syncthreads();
    int base = blockIdx.x * EPB;
    for (int k = 0; k < EPB; k += 256) {
        int t = base + k + threadIdx.x;
        if (t < ET) atomicAdd(&h[dst32[t] >> BKT_SHIFT], 1);
    }
    __syncthreads();
    for (int i = threadIdx.x; i < NBKT; i += 256) {
        int c = h[i];
        bbase[i] = c ? atomicAdd(&bucket_fill[i], c) : 0;
        h[i] = 0;  // becomes local fill counter (same thread owns bin -> no race)
    }
    __syncthreads();
    for (int k = 0; k < EPB; k += 256) {
        int t = base + k + threadIdx.x;
        if (t < ET) {
            int sv = src32[t], dv = dst32[t];
            int b = dv >> BKT_SHIFT;
            int off = atomicAdd(&h[b], 1);
            pairs[bbase[b] + off] = make_int2(sv, dv);
        }
    }
}

// ---- stage B: per-bucket fine CSR (1024 nodes in LDS) + in-bucket scatter of src ----
__global__ __launch_bounds__(512) void k_bkt_csr(const int2* __restrict__ pairs, const int* __restrict__ bucket_fill,
                                                 int* __restrict__ rowptr, int* __restrict__ rowend,
                                                 int* __restrict__ deg, int* __restrict__ src_sorted) {
    __shared__ int h[1024];
    __shared__ int tmp[512];
    int t = threadIdx.x;
    int b = blockIdx.x;
    int e0 = b * CAP, e1 = bucket_fill[b];
    int node0 = b << BKT_SHIFT;

    h[t] = 0;
    h[t + 512] = 0;
    __syncthreads();
    for (int e = e0 + t; e < e1; e += 512) atomicAdd(&h[pairs[e].y & BKT_MASK], 1);
    __syncthreads();

    int i0 = 2 * t, i1 = 2 * t + 1;
    int v0 = h[i0], v1 = h[i1];
    int s = v0 + v1;
    tmp[t] = s;
    for (int off = 1; off < 512; off <<= 1) {
        __syncthreads();
        int u = (t >= off) ? tmp[t - off] : 0;
        __syncthreads();
        tmp[t] += u;
    }
    __syncthreads();
    int excl = tmp[t] - s;
    h[i0] = excl;
    h[i1] = excl + v0;
    __syncthreads();

    int n0 = node0 + i0, n1 = node0 + i1;
    if (n0 < NN) { rowptr[n0] = e0 + excl;      rowend[n0] = e0 + excl + v0;      deg[n0] = v0; }
    if (n1 < NN) { rowptr[n1] = e0 + excl + v0; rowend[n1] = e0 + excl + v0 + v1; deg[n1] = v1; }
    __syncthreads();

    for (int e = e0 + t; e < e1; e += 512) {
        int2 p = pairs[e];
        int sl = atomicAdd(&h[p.y & BKT_MASK], 1);
        src_sorted[e0 + sl] = p.x;
    }
}

// ---- degree counting sort: LDS-hist histogram / wave scan / LDS-chunk fill ----
__global__ __launch_bounds__(256) void k_dhist(const int* __restrict__ deg, int* __restrict__ dcnt) {
    __shared__ int h[64];
    if (threadIdx.x < 64) h[threadIdx.x] = 0;
    __syncthreads();
    int t = blockIdx.x * 256 + threadIdx.x;
    if (t < NN) atomicAdd(&h[min(deg[t], 63)], 1);
    __syncthreads();
    if (threadIdx.x < 64) {
        int c = h[threadIdx.x];
        if (c) atomicAdd(&dcnt[threadIdx.x], c);
    }
}

__global__ __launch_bounds__(64) void k_dscan(const int* __restrict__ dcnt, int* __restrict__ dfill) {
    int t = threadIdx.x;  // 64 threads, one wave
    int c = dcnt[t];
    int v = c;
    for (int off = 1; off < 64; off <<= 1) {
        int u = __shfl_up(v, off, 64);
        if (t >= off) v += u;
    }
    dfill[t] = v - c;  // exclusive
}

__global__ __launch_bounds__(256) void k_dfill(const int* __restrict__ deg, int* __restrict__ dfill,
                                               int* __restrict__ order) {
    __shared__ int h[64];
    __shared__ int bbase[64];
    if (threadIdx.x < 64) h[threadIdx.x] = 0;
    __syncthreads();
    int t = blockIdx.x * 256 + threadIdx.x;
    int bin = -1;
    if (t < NN) {
        bin = min(deg[t], 63);
        atomicAdd(&h[bin], 1);
    }
    __syncthreads();
    if (threadIdx.x < 64) {
        int c = h[threadIdx.x];
        bbase[threadIdx.x] = c ? atomicAdd(&dfill[threadIdx.x], c) : 0;
        h[threadIdx.x] = 0;  // local fill counter
    }
    __syncthreads();
    if (t < NN) {
        int off = atomicAdd(&h[bin], 1);
        order[bbase[bin] + off] = t;
    }
}

// ---- helpers ----
__device__ __forceinline__ void acc8(uint4 r, float* c) {
    float2 f0 = __half22float2(*reinterpret_cast<__half2*>(&r.x));
    float2 f1 = __half22float2(*reinterpret_cast<__half2*>(&r.y));
    float2 f2 = __half22float2(*reinterpret_cast<__half2*>(&r.z));
    float2 f3 = __half22float2(*reinterpret_cast<__half2*>(&r.w));
    c[0] += f0.x; c[1] += f0.y; c[2] += f1.x; c[3] += f1.y;
    c[4] += f2.x; c[5] += f2.y; c[6] += f3.x; c[7] += f3.y;
}

// ---- layer 1 fused: thread-per-node (degree-sorted) pull-agg + 1->32 linear + relu ----
__global__ __launch_bounds__(256) void k_pull1(const int* __restrict__ order,
                                               const int* __restrict__ rowptr, const int* __restrict__ rowend,
                                               const int* __restrict__ src_sorted,
                                               const float* __restrict__ x0, const float* __restrict__ W1,
                                               const float* __restrict__ b1, __half* __restrict__ hout) {
    __shared__ float W1l[32], b1l[32];
    if (threadIdx.x < 32) {
        W1l[threadIdx.x] = W1[threadIdx.x];
        b1l[threadIdx.x] = b1[threadIdx.x];
    }
    __syncthreads();
    int gid = blockIdx.x * 256 + threadIdx.x;
    if (gid >= NN) return;
    int g = order[gid];
    int e0 = rowptr[g], e1 = rowend[g];
    float a0 = x0[g], a1 = 0.f, a2 = 0.f, a3 = 0.f, a4 = 0.f, a5 = 0.f, a6 = 0.f, a7 = 0.f;
    int e = e0;
    for (; e + 8 <= e1; e += 8) {
        a0 += x0[src_sorted[e + 0]];
        a1 += x0[src_sorted[e + 1]];
        a2 += x0[src_sorted[e + 2]];
        a3 += x0[src_sorted[e + 3]];
        a4 += x0[src_sorted[e + 4]];
        a5 += x0[src_sorted[e + 5]];
        a6 += x0[src_sorted[e + 6]];
        a7 += x0[src_sorted[e + 7]];
    }
    for (; e < e1; ++e) a0 += x0[src_sorted[e]];
    float s = ((a0 + a1) + (a2 + a3)) + ((a4 + a5) + (a6 + a7));

    uint4* orow = reinterpret_cast<uint4*>(hout) + ((size_t)g << 2);
#pragma unroll
    for (int q = 0; q < 4; ++q) {
        float o0 = fmaxf(fmaf(s, W1l[8 * q + 0], b1l[8 * q + 0]), 0.f);
        float o1 = fmaxf(fmaf(s, W1l[8 * q + 1], b1l[8 * q + 1]), 0.f);
        float o2 = fmaxf(fmaf(s, W1l[8 * q + 2], b1l[8 * q + 2]), 0.f);
        float o3 = fmaxf(fmaf(s, W1l[8 * q + 3], b1l[8 * q + 3]), 0.f);
        float o4 = fmaxf(fmaf(s, W1l[8 * q + 4], b1l[8 * q + 4]), 0.f);
        float o5 = fmaxf(fmaf(s, W1l[8 * q + 5], b1l[8 * q + 5]), 0.f);
        float o6 = fmaxf(fmaf(s, W1l[8 * q + 6], b1l[8 * q + 6]), 0.f);
        float o7 = fmaxf(fmaf(s, W1l[8 * q + 7], b1l[8 * q + 7]), 0.f);
        __half2 p0 = __floats2half2_rn(o0, o1);
        __half2 p1 = __floats2half2_rn(o2, o3);
        __half2 p2 = __floats2half2_rn(o4, o5);
        __half2 p3 = __floats2half2_rn(o6, o7);
        orow[q] = make_uint4(*reinterpret_cast<unsigned*>(&p0), *reinterpret_cast<unsigned*>(&p1),
                             *reinterpret_cast<unsigned*>(&p2), *reinterpret_cast<unsigned*>(&p3));
    }
}

// ---- fused pull-agg + 32x32 matmul (+relu), 4 lanes/node (degree-sorted), uint4 gathers ----
template <int RELU>
__global__ __launch_bounds__(256) void k_agg_mm(const int* __restrict__ order,
                                                const int* __restrict__ rowptr, const int* __restrict__ rowend,
                                                const int* __restrict__ src_sorted,
                                                const __half* __restrict__ hin, const float* __restrict__ W,
                                                const float* __restrict__ b, __half* __restrict__ hout) {
    __shared__ float Wl[1024];
    for (int i = threadIdx.x; i < 1024; i += 256) Wl[i] = W[i];
    __syncthreads();
    int gid = (blockIdx.x * 256 + threadIdx.x) >> 2;   // 64 nodes/block
    if (gid >= NN) return;
    int g = order[gid];
    int j = threadIdx.x & 3;
    const uint4* tab = reinterpret_cast<const uint4*>(hin);
    int e0 = rowptr[g], e1 = rowend[g];
    float x[8], y[8];
#pragma unroll
    for (int i = 0; i < 8; ++i) { x[i] = 0.f; y[i] = 0.f; }
    acc8(tab[(g << 2) + j], x);  // self term
    int e = e0;
    for (; e + 8 <= e1; e += 8) {
        int s0 = src_sorted[e + 0], s1 = src_sorted[e + 1], s2 = src_sorted[e + 2], s3 = src_sorted[e + 3];
        int s4 = src_sorted[e + 4], s5 = src_sorted[e + 5], s6 = src_sorted[e + 6], s7 = src_sorted[e + 7];
        uint4 r0 = tab[(s0 << 2) + j];
        uint4 r1 = tab[(s1 << 2) + j];
        uint4 r2 = tab[(s2 << 2) + j];
        uint4 r3 = tab[(s3 << 2) + j];
        uint4 r4 = tab[(s4 << 2) + j];
        uint4 r5 = tab[(s5 << 2) + j];
        uint4 r6 = tab[(s6 << 2) + j];
        uint4 r7 = tab[(s7 << 2) + j];
        acc8(r0, x); acc8(r1, y); acc8(r2, x); acc8(r3, y);
        acc8(r4, x); acc8(r5, y); acc8(r6, x); acc8(r7, y);
    }
    for (; e < e1; ++e) acc8(tab[(src_sorted[e] << 2) + j], x);
#pragma unroll
    for (int i = 0; i < 8; ++i) x[i] += y[i];

    float o[8];
#pragma unroll
    for (int i = 0; i < 8; ++i) o[i] = b[8 * j + i];
#pragma unroll
    for (int sl = 0; sl < 4; ++sl) {
#pragma unroll
        for (int r = 0; r < 8; ++r) {
            float xk = __shfl(x[r], sl, 4);
            int k = 8 * sl + r;
            float4 w0 = *reinterpret_cast<const float4*>(&Wl[k * 32 + 8 * j]);
            float4 w1 = *reinterpret_cast<const float4*>(&Wl[k * 32 + 8 * j + 4]);
            o[0] = fmaf(xk, w0.x, o[0]); o[1] = fmaf(xk, w0.y, o[1]);
            o[2] = fmaf(xk, w0.z, o[2]); o[3] = fmaf(xk, w0.w, o[3]);
            o[4] = fmaf(xk, w1.x, o[4]); o[5] = fmaf(xk, w1.y, o[5]);
            o[6] = fmaf(xk, w1.z, o[6]); o[7] = fmaf(xk, w1.w, o[7]);
        }
    }
    if (RELU) {
#pragma unroll
        for (int i = 0; i < 8; ++i) o[i] = fmaxf(o[i], 0.f);
    }
    __half2 p0 = __floats2half2_rn(o[0], o[1]);
    __half2 p1 = __floats2half2_rn(o[2], o[3]);
    __half2 p2 = __floats2half2_rn(o[4], o[5]);
    __half2 p3 = __floats2half2_rn(o[6], o[7]);
    uint4 st = make_uint4(*reinterpret_cast<unsigned*>(&p0), *reinterpret_cast<unsigned*>(&p1),
                          *reinterpret_cast<unsigned*>(&p2), *reinterpret_cast<unsigned*>(&p3));
    reinterpret_cast<uint4*>(hout)[(g << 2) + j] = st;
}

// ---- layer 4 fused: pull-agg + W3 matmul + W5 projections -> u16 (b5 folded), v16 ----
__global__ __launch_bounds__(256) void k_agg_mm_proj(const int* __restrict__ order,
                                                     const int* __restrict__ rowptr, const int* __restrict__ rowend,
                                                     const int* __restrict__ src_sorted,
                                                     const __half* __restrict__ hin, const float* __restrict__ W3,
                                                     const float* __restrict__ b3,
                                                     const float* __restrict__ W5, const float* __restrict__ b5,
                                                     __half* __restrict__ u16, __half* __restrict__ v16) {
    __shared__ float W3l[1024];
    __shared__ float W5l[2048];
    for (int i = threadIdx.x; i < 1024; i += 256) W3l[i] = W3[i];
    for (int i = threadIdx.x; i < 2048; i += 256) W5l[i] = W5[i];
    __syncthreads();
    int gid = (blockIdx.x * 256 + threadIdx.x) >> 2;
    if (gid >= NN) return;
    int g = order[gid];
    int j = threadIdx.x & 3;
    const uint4* tab = reinterpret_cast<const uint4*>(hin);
    int e0 = rowptr[g], e1 = rowend[g];
    float x[8], y[8];
#pragma unroll
    for (int i = 0; i < 8; ++i) { x[i] = 0.f; y[i] = 0.f; }
    acc8(tab[(g << 2) + j], x);  // self term
    int e = e0;
    for (; e + 8 <= e1; e += 8) {
        int s0 = src_sorted[e + 0], s1 = src_sorted[e + 1], s2 = src_sorted[e + 2], s3 = src_sorted[e + 3];
        int s4 = src_sorted[e + 4], s5 = src_sorted[e + 5], s6 = src_sorted[e + 6], s7 = src_sorted[e + 7];
        uint4 r0 = tab[(s0 << 2) + j];
        uint4 r1 = tab[(s1 << 2) + j];
        uint4 r2 = tab[(s2 << 2) + j];
        uint4 r3 = tab[(s3 << 2) + j];
        uint4 r4 = tab[(s4 << 2) + j];
        uint4 r5 = tab[(s5 << 2) + j];
        uint4 r6 = tab[(s6 << 2) + j];
        uint4 r7 = tab[(s7 << 2) + j];
        acc8(r0, x); acc8(r1, y); acc8(r2, x); acc8(r3, y);
        acc8(r4, x); acc8(r5, y); acc8(r6, x); acc8(r7, y);
    }
    for (; e < e1; ++e) acc8(tab[(src_sorted[e] << 2) + j], x);
#pragma unroll
    for (int i = 0; i < 8; ++i) x[i] += y[i];

    // x4 = agg . W3 + b3 (no relu)
    float o[8];
#pragma unroll
    for (int i = 0; i < 8; ++i) o[i] = b3[8 * j + i];
#pragma unroll
    for (int sl = 0; sl < 4; ++sl) {
#pragma unroll
        for (int r = 0; r < 8; ++r) {
            float xk = __shfl(x[r], sl, 4);
            int k = 8 * sl + r;
            float4 w0 = *reinterpret_cast<const float4*>(&W3l[k * 32 + 8 * j]);
            float4 w1 = *reinterpret_cast<const float4*>(&W3l[k * 32 + 8 * j + 4]);
            o[0] = fmaf(xk, w0.x, o[0]); o[1] = fmaf(xk, w0.y, o[1]);
            o[2] = fmaf(xk, w0.z, o[2]); o[3] = fmaf(xk, w0.w, o[3]);
            o[4] = fmaf(xk, w1.x, o[4]); o[5] = fmaf(xk, w1.y, o[5]);
            o[6] = fmaf(xk, w1.z, o[6]); o[7] = fmaf(xk, w1.w, o[7]);
        }
    }
    // u = x4 . W5[0:32,:] + b5 ; v = x4 . W5[32:64,:]
    float u[8], v[8];
#pragma unroll
    for (int i = 0; i < 8; ++i) { u[i] = b5[8 * j + i]; v[i] = 0.f; }
#pragma unroll
    for (int sl = 0; sl < 4; ++sl) {
#pragma unroll
        for (int r = 0; r < 8; ++r) {
            float xk = __shfl(o[r], sl, 4);
            int k = 8 * sl + r;
            float4 a0 = *reinterpret_cast<const float4*>(&W5l[k * 32 + 8 * j]);
            float4 a1 = *reinterpret_cast<const float4*>(&W5l[k * 32 + 8 * j + 4]);
            u[0] = fmaf(xk, a0.x, u[0]); u[1] = fmaf(xk, a0.y, u[1]);
            u[2] = fmaf(xk, a0.z, u[2]); u[3] = fmaf(xk, a0.w, u[3]);
            u[4] = fmaf(xk, a1.x, u[4]); u[5] = fmaf(xk, a1.y, u[5]);
            u[6] = fmaf(xk, a1.z, u[6]); u[7] = fmaf(xk, a1.w, u[7]);
            float4 c0 = *reinterpret_cast<const float4*>(&W5l[(32 + k) * 32 + 8 * j]);
            float4 c1 = *reinterpret_cast<const float4*>(&W5l[(32 + k) * 32 + 8 * j + 4]);
            v[0] = fmaf(xk, c0.x, v[0]); v[1] = fmaf(xk, c0.y, v[1]);
            v[2] = fmaf(xk, c0.z, v[2]); v[3] = fmaf(xk, c0.w, v[3]);
            v[4] = fmaf(xk, c1.x, v[4]); v[5] = fmaf(xk, c1.y, v[5]);
            v[6] = fmaf(xk, c1.z, v[6]); v[7] = fmaf(xk, c1.w, v[7]);
        }
    }
    __half2 pu0 = __floats2half2_rn(u[0], u[1]);
    __half2 pu1 = __floats2half2_rn(u[2], u[3]);
    __half2 pu2 = __floats2half2_rn(u[4], u[5]);
    __half2 pu3 = __floats2half2_rn(u[6], u[7]);
    uint4 su = make_uint4(*reinterpret_cast<unsigned*>(&pu0), *reinterpret_cast<unsigned*>(&pu1),
                          *reinterpret_cast<unsigned*>(&pu2), *reinterpret_cast<unsigned*>(&pu3));
    reinterpret_cast<uint4*>(u16)[(g << 2) + j] = su;
    __half2 pv0 = __floats2half2_rn(v[0], v[1]);
    __half2 pv1 = __floats2half2_rn(v[2], v[3]);
    __half2 pv2 = __floats2half2_rn(v[4], v[5]);
    __half2 pv3 = __floats2half2_rn(v[6], v[7]);
    uint4 sv = make_uint4(*reinterpret_cast<unsigned*>(&pv0), *reinterpret_cast<unsigned*>(&pv1),
                          *reinterpret_cast<unsigned*>(&pv2), *reinterpret_cast<unsigned*>(&pv3));
    reinterpret_cast<uint4*>(v16)[(g << 2) + j] = sv;
}

// ---- per-edge (2 edges/thread): ALL 16 row-loads hoisted & fenced, then compute ----
__global__ __launch_bounds__(256) void k_edge(const int* __restrict__ src32, const int* __restrict__ dst32,
                                              const __half* __restrict__ u16, const __half* __restrict__ v16,
                                              const float* __restrict__ W6, const float* __restrict__ b6,
                                              float* __restrict__ pd_out, float* __restrict__ partial) {
    int ea = blockIdx.x * 512 + threadIdx.x;   // EE divisible by 512
    int eb = ea + 256;
    int sa = src32[ea], da = dst32[ea];
    int sb = src32[eb], db = dst32[eb];
    const uint4* pua = reinterpret_cast<const uint4*>(u16 + ((size_t)sa << 5));
    const uint4* pva = reinterpret_cast<const uint4*>(v16 + ((size_t)da << 5));
    const uint4* pub = reinterpret_cast<const uint4*>(u16 + ((size_t)sb << 5));
    const uint4* pvb = reinterpret_cast<const uint4*>(v16 + ((size_t)db << 5));

    // hoist all 16 16B gathers into registers; fence so the compiler can't sink them
    uint4 A[4], B[4], C[4], D[4];
#pragma unroll
    for (int q = 0; q < 4; ++q) A[q] = pua[q];
#pragma unroll
    for (int q = 0; q < 4; ++q) B[q] = pva[q];
#pragma unroll
    for (int q = 0; q < 4; ++q) C[q] = pub[q];
#pragma unroll
    for (int q = 0; q < 4; ++q) D[q] = pvb[q];
    __builtin_amdgcn_sched_barrier(0);

    float b60 = b6[0], b61 = b6[1];
    float pda0 = b60, pda1 = b61, pdb0 = b60, pdb1 = b61;
#pragma unroll
    for (int q = 0; q < 4; ++q) {
        const __half2* ah = reinterpret_cast<const __half2*>(&A[q]);
        const __half2* bh = reinterpret_cast<const __half2*>(&B[q]);
        const __half2* ch = reinterpret_cast<const __half2*>(&C[q]);
        const __half2* dh = reinterpret_cast<const __half2*>(&D[q]);
#pragma unroll
        for (int r = 0; r < 4; ++r) {
            float2 fA = __half22float2(__hadd2(ah[r], bh[r]));
            float2 fB = __half22float2(__hadd2(ch[r], dh[r]));
            int jj = q * 8 + 2 * r;
            float w00 = W6[2 * jj + 0], w01 = W6[2 * jj + 1];
            float w10 = W6[2 * (jj + 1) + 0], w11 = W6[2 * (jj + 1) + 1];
            float hA0 = fA.x >= 0.f ? fA.x : 0.1f * fA.x;
            float hA1 = fA.y >= 0.f ? fA.y : 0.1f * fA.y;
            float hB0 = fB.x >= 0.f ? fB.x : 0.1f * fB.x;
            float hB1 = fB.y >= 0.f ? fB.y : 0.1f * fB.y;
            pda0 = fmaf(hA0, w00, pda0); pda1 = fmaf(hA0, w01, pda1);
            pda0 = fmaf(hA1, w10, pda0); pda1 = fmaf(hA1, w11, pda1);
            pdb0 = fmaf(hB0, w00, pdb0); pdb1 = fmaf(hB0, w01, pdb1);
            pdb0 = fmaf(hB1, w10, pdb0); pdb1 = fmaf(hB1, w11, pdb1);
        }
    }
    reinterpret_cast<float2*>(pd_out)[ea] = make_float2(pda0, pda1);
    reinterpret_cast<float2*>(pd_out)[eb] = make_float2(pdb0, pdb1);

    float persA = pda1 - pda0;
    float persB = pdb1 - pdb0;
    const float inv = 3.5355339059327378f;  // 1/(0.2*sqrt(2))
    float cbA[6], cpA[6], cbB[6], cpB[6];
#pragma unroll
    for (int i = 0; i < 6; ++i) {
        float te = 0.2f * (float)i;
        cbA[i] = erff((te - pda0) * inv);
        cpA[i] = erff((te - persA) * inv);
        cbB[i] = erff((te - pdb0) * inv);
        cpB[i] = erff((te - persB) * inv);
    }

    int lane = threadIdx.x & 63;
    int wv = threadIdx.x >> 6;
    __shared__ float sacc[4][25];
#pragma unroll
    for (int i = 0; i < 5; ++i) {
        float pa = 0.25f * persA * (cbA[i + 1] - cbA[i]);
        float pb = 0.25f * persB * (cbB[i + 1] - cbB[i]);
#pragma unroll
        for (int jj = 0; jj < 5; ++jj) {
            float v = pa * (cpA[jj + 1] - cpA[jj]) + pb * (cpB[jj + 1] - cpB[jj]);
            v += __shfl_down(v, 32);
            v += __shfl_down(v, 16);
            v += __shfl_down(v, 8);
            v += __shfl_down(v, 4);
            v += __shfl_down(v, 2);
            v += __shfl_down(v, 1);
            if (lane == 0) sacc[wv][i * 5 + jj] = v;
        }
    }
    __syncthreads();
    if (threadIdx.x < 25) {
        partial[(size_t)blockIdx.x * 25 + threadIdx.x] =
            sacc[0][threadIdx.x] + sacc[1][threadIdx.x] + sacc[2][threadIdx.x] + sacc[3][threadIdx.x];
    }
}

// ---- deterministic final reduction of block partials per bin ----
__global__ __launch_bounds__(256) void k_img(const float* __restrict__ partial, float* __restrict__ img) {
    int bin = blockIdx.x;  // 25 blocks
    float s = 0.f;
    for (int k = threadIdx.x; k < EE / 512; k += 256) s += partial[(size_t)k * 25 + bin];
    s += __shfl_down(s, 32);
    s += __shfl_down(s, 16);
    s += __shfl_down(s, 8);
    s += __shfl_down(s, 4);
    s += __shfl_down(s, 2);
    s += __shfl_down(s, 1);
    __shared__ float wsum[4];
    if ((threadIdx.x & 63) == 0) wsum[threadIdx.x >> 6] = s;
    __syncthreads();
    if (threadIdx.x == 0) img[bin] = wsum[0] + wsum[1] + wsum[2] + wsum[3];
}

extern "C" void kernel_launch(void* const* d_in, const int* in_sizes, int n_in,
                              void* d_out, int out_size, void* d_ws, size_t ws_size,
                              hipStream_t stream) {
    const float* x0 = (const float*)d_in[0];
    // Harness converts integer inputs to int32: edge_index0 is (2, ET) int32.
    const int* src32 = (const int*)d_in[1];
    const int* dst32 = src32 + ET;
    const float* W1 = (const float*)d_in[2];
    const float* b1 = (const float*)d_in[3];
    const float* W2 = (const float*)d_in[4];
    const float* b2 = (const float*)d_in[5];
    const float* W4 = (const float*)d_in[6];
    const float* b4 = (const float*)d_in[7];
    const float* W3 = (const float*)d_in[8];
    const float* b3 = (const float*)d_in[9];
    const float* W5 = (const float*)d_in[10];
    const float* b5 = (const float*)d_in[11];
    const float* W6 = (const float*)d_in[12];
    const float* b6 = (const float*)d_in[13];
    float* out = (float*)d_out;

    const size_t PADDED = (size_t)NBKT * CAP;        // 1,856,512
    char* w = (char*)d_ws;
    int2* pairs = (int2*)w;                          // PADDED int2
    int* src_sorted = (int*)(pairs + PADDED);        // PADDED
    int* bucket_fill = src_sorted + PADDED;          // NBKT
    int* dcnt = bucket_fill + NBKT;                  // 64
    int* dfill = dcnt + 64;                          // 64
    int* rowptr = dfill + 64;                        // NN
    int* rowend = rowptr + NN;                       // NN
    int* deg = rowend + NN;                          // NN
    int* order = deg + NN;                           // NN
    size_t off = ((size_t)((char*)(order + NN) - w) + 63) & ~(size_t)63;
    __half* bufA = (__half*)(w + off);               // NN*32 halfs
    __half* bufB = bufA + (size_t)NN * 32;           // NN*32 halfs
    __half* u16 = bufB + (size_t)NN * 32;            // NN*32 halfs
    __half* v16 = u16 + (size_t)NN * 32;             // NN*32 halfs
    float* partial = (float*)(v16 + (size_t)NN * 32);// (EE/512)*25 floats

    // ---- build CSR via padded-bucket counting sort (no count pass) ----
    k_seed<<<1, 128, 0, stream>>>(bucket_fill, dcnt);
    k_bkt_scatter<<<NBLK_A, 256, 0, stream>>>(src32, dst32, bucket_fill, pairs);
    k_bkt_csr<<<NBKT, 512, 0, stream>>>(pairs, bucket_fill, rowptr, rowend, deg, src_sorted);

    // ---- degree counting sort -> order[] (LDS-hist, low-contention) ----
    k_dhist<<<NBLK_N, 256, 0, stream>>>(deg, dcnt);
    k_dscan<<<1, 64, 0, stream>>>(dcnt, dfill);
    k_dfill<<<NBLK_N, 256, 0, stream>>>(deg, dfill, order);

    // ---- layer 1 (fused agg + expand, degree-sorted) ----
    k_pull1<<<(NN + 255) / 256, 256, 0, stream>>>(order, rowptr, rowend, src_sorted, x0, W1, b1, bufA);
    // ---- layers 2-3 (4 lanes/node, uint4 gathers, degree-sorted) ----
    k_agg_mm<1><<<(NN * 4 + 255) / 256, 256, 0, stream>>>(order, rowptr, rowend, src_sorted, bufA, W2, b2, bufB);
    k_agg_mm<1><<<(NN * 4 + 255) / 256, 256, 0, stream>>>(order, rowptr, rowend, src_sorted, bufB, W4, b4, bufA);
    // ---- layer 4 + W5 projections ----
    k_agg_mm_proj<<<(NN * 4 + 255) / 256, 256, 0, stream>>>(order, rowptr, rowend, src_sorted, bufA, W3, b3, W5, b5, u16, v16);

    // ---- edge MLP + persistence image (original order) ----
    k_edge<<<EE / 512, 256, 0, stream>>>(src32, dst32, u16, v16, W6, b6, out, partial);
    k_img<<<25, 256, 0, stream>>>(partial, out + 2 * (size_t)EE);
}

// Round 14
// 239.765 us; speedup vs baseline: 3.4016x; 1.0402x over previous
//
#include <hip/hip_runtime.h>
#include <hip/hip_bf16.h>
#include <hip/hip_fp16.h>
#include <math.h>

#define NN 100000
#define EE 1600000
#define ET 1700000   // E + N self-loops
#define HID 32

#define BKT_SHIFT 10
#define BKT_MASK 1023
#define NBKT 98            // ceil(NN / 1024)
#define CAP 18944          // padded bucket capacity (mean 17347 + ~12 sigma)
#define EPB 4096           // edges per block in stage A
#define NBLK_A 416         // ceil(ET / EPB)
#define NBI 1024           // blocks for img kernel

// ---- seed bucket bases ----
__global__ __launch_bounds__(128) void k_seed(int* __restrict__ bucket_fill) {
    int t = threadIdx.x;
    if (t < NBKT) bucket_fill[t] = t * CAP;
}

// ---- stage A: scatter (src,dst) pairs into padded bucket regions (block-chunk reserved) ----
__global__ __launch_bounds__(256) void k_bkt_scatter(const int* __restrict__ src32, const int* __restrict__ dst32,
                                                     int* __restrict__ bucket_fill, int2* __restrict__ pairs) {
    __shared__ int h[NBKT];
    __shared__ int bbase[NBKT];
    for (int i = threadIdx.x; i < NBKT; i += 256) h[i] = 0;
    __syncthreads();
    int base = blockIdx.x * EPB;
    for (int k = 0; k < EPB; k += 256) {
        int t = base + k + threadIdx.x;
        if (t < ET) atomicAdd(&h[dst32[t] >> BKT_SHIFT], 1);
    }
    __syncthreads();
    for (int i = threadIdx.x; i < NBKT; i += 256) {
        int c = h[i];
        bbase[i] = c ? atomicAdd(&bucket_fill[i], c) : 0;
        h[i] = 0;  // becomes local fill counter (same thread owns bin -> no race)
    }
    __syncthreads();
    for (int k = 0; k < EPB; k += 256) {
        int t = base + k + threadIdx.x;
        if (t < ET) {
            int sv = src32[t], dv = dst32[t];
            int b = dv >> BKT_SHIFT;
            int off = atomicAdd(&h[b], 1);
            pairs[bbase[b] + off] = make_int2(sv, dv);
        }
    }
}

// ---- stage B: per-bucket fine CSR (1024 nodes in LDS) + in-bucket scatter of src ----
__global__ __launch_bounds__(512) void k_bkt_csr(const int2* __restrict__ pairs, const int* __restrict__ bucket_fill,
                                                 int* __restrict__ rowptr, int* __restrict__ rowend,
                                                 int* __restrict__ src_sorted) {
    __shared__ int h[1024];
    __shared__ int tmp[512];
    int t = threadIdx.x;
    int b = blockIdx.x;
    int e0 = b * CAP, e1 = bucket_fill[b];
    int node0 = b << BKT_SHIFT;

    h[t] = 0;
    h[t + 512] = 0;
    __syncthreads();
    for (int e = e0 + t; e < e1; e += 512) atomicAdd(&h[pairs[e].y & BKT_MASK], 1);
    __syncthreads();

    int i0 = 2 * t, i1 = 2 * t + 1;
    int v0 = h[i0], v1 = h[i1];
    int s = v0 + v1;
    tmp[t] = s;
    for (int off = 1; off < 512; off <<= 1) {
        __syncthreads();
        int u = (t >= off) ? tmp[t - off] : 0;
        __syncthreads();
        tmp[t] += u;
    }
    __syncthreads();
    int excl = tmp[t] - s;
    h[i0] = excl;
    h[i1] = excl + v0;
    __syncthreads();

    int n0 = node0 + i0, n1 = node0 + i1;
    if (n0 < NN) { rowptr[n0] = e0 + excl;      rowend[n0] = e0 + excl + v0; }
    if (n1 < NN) { rowptr[n1] = e0 + excl + v0; rowend[n1] = e0 + excl + v0 + v1; }
    __syncthreads();

    for (int e = e0 + t; e < e1; e += 512) {
        int2 p = pairs[e];
        int sl = atomicAdd(&h[p.y & BKT_MASK], 1);
        src_sorted[e0 + sl] = p.x;
    }
}

// ---- helpers ----
__device__ __forceinline__ void acc8(uint4 r, float* c) {
    float2 f0 = __half22float2(*reinterpret_cast<__half2*>(&r.x));
    float2 f1 = __half22float2(*reinterpret_cast<__half2*>(&r.y));
    float2 f2 = __half22float2(*reinterpret_cast<__half2*>(&r.z));
    float2 f3 = __half22float2(*reinterpret_cast<__half2*>(&r.w));
    c[0] += f0.x; c[1] += f0.y; c[2] += f1.x; c[3] += f1.y;
    c[4] += f2.x; c[5] += f2.y; c[6] += f3.x; c[7] += f3.y;
}

// ---- layer 1 fused: thread-per-node scalar pull-agg + 1->32 linear + relu -> fp16 row ----
__global__ __launch_bounds__(256) void k_pull1(const int* __restrict__ rowptr, const int* __restrict__ rowend,
                                               const int* __restrict__ src_sorted,
                                               const float* __restrict__ x0, const float* __restrict__ W1,
                                               const float* __restrict__ b1, __half* __restrict__ hout) {
    __shared__ float W1l[32], b1l[32];
    if (threadIdx.x < 32) {
        W1l[threadIdx.x] = W1[threadIdx.x];
        b1l[threadIdx.x] = b1[threadIdx.x];
    }
    __syncthreads();
    int g = blockIdx.x * 256 + threadIdx.x;
    if (g >= NN) return;
    int e0 = rowptr[g], e1 = rowend[g];
    float a0 = x0[g], a1 = 0.f, a2 = 0.f, a3 = 0.f, a4 = 0.f, a5 = 0.f, a6 = 0.f, a7 = 0.f;
    int e = e0;
    for (; e + 8 <= e1; e += 8) {
        a0 += x0[src_sorted[e + 0]];
        a1 += x0[src_sorted[e + 1]];
        a2 += x0[src_sorted[e + 2]];
        a3 += x0[src_sorted[e + 3]];
        a4 += x0[src_sorted[e + 4]];
        a5 += x0[src_sorted[e + 5]];
        a6 += x0[src_sorted[e + 6]];
        a7 += x0[src_sorted[e + 7]];
    }
    for (; e < e1; ++e) a0 += x0[src_sorted[e]];
    float s = ((a0 + a1) + (a2 + a3)) + ((a4 + a5) + (a6 + a7));

    uint4* orow = reinterpret_cast<uint4*>(hout) + ((size_t)g << 2);
#pragma unroll
    for (int q = 0; q < 4; ++q) {
        float o0 = fmaxf(fmaf(s, W1l[8 * q + 0], b1l[8 * q + 0]), 0.f);
        float o1 = fmaxf(fmaf(s, W1l[8 * q + 1], b1l[8 * q + 1]), 0.f);
        float o2 = fmaxf(fmaf(s, W1l[8 * q + 2], b1l[8 * q + 2]), 0.f);
        float o3 = fmaxf(fmaf(s, W1l[8 * q + 3], b1l[8 * q + 3]), 0.f);
        float o4 = fmaxf(fmaf(s, W1l[8 * q + 4], b1l[8 * q + 4]), 0.f);
        float o5 = fmaxf(fmaf(s, W1l[8 * q + 5], b1l[8 * q + 5]), 0.f);
        float o6 = fmaxf(fmaf(s, W1l[8 * q + 6], b1l[8 * q + 6]), 0.f);
        float o7 = fmaxf(fmaf(s, W1l[8 * q + 7], b1l[8 * q + 7]), 0.f);
        __half2 p0 = __floats2half2_rn(o0, o1);
        __half2 p1 = __floats2half2_rn(o2, o3);
        __half2 p2 = __floats2half2_rn(o4, o5);
        __half2 p3 = __floats2half2_rn(o6, o7);
        orow[q] = make_uint4(*reinterpret_cast<unsigned*>(&p0), *reinterpret_cast<unsigned*>(&p1),
                             *reinterpret_cast<unsigned*>(&p2), *reinterpret_cast<unsigned*>(&p3));
    }
}

// ---- fused pull-agg + 32x32 matmul (+relu), 4 lanes/node, uint4 gathers, 8-deep ILP ----
template <int RELU>
__global__ __launch_bounds__(256) void k_agg_mm(const int* __restrict__ rowptr, const int* __restrict__ rowend,
                                                const int* __restrict__ src_sorted,
                                                const __half* __restrict__ hin, const float* __restrict__ W,
                                                const float* __restrict__ b, __half* __restrict__ hout) {
    __shared__ float Wl[1024];
    for (int i = threadIdx.x; i < 1024; i += 256) Wl[i] = W[i];
    __syncthreads();
    int g = (blockIdx.x * 256 + threadIdx.x) >> 2;   // 64 nodes/block
    if (g >= NN) return;
    int j = threadIdx.x & 3;
    const uint4* tab = reinterpret_cast<const uint4*>(hin);
    int e0 = rowptr[g], e1 = rowend[g];
    float x[8], y[8];
#pragma unroll
    for (int i = 0; i < 8; ++i) { x[i] = 0.f; y[i] = 0.f; }
    acc8(tab[(g << 2) + j], x);  // self term
    int e = e0;
    for (; e + 8 <= e1; e += 8) {
        int s0 = src_sorted[e + 0], s1 = src_sorted[e + 1], s2 = src_sorted[e + 2], s3 = src_sorted[e + 3];
        int s4 = src_sorted[e + 4], s5 = src_sorted[e + 5], s6 = src_sorted[e + 6], s7 = src_sorted[e + 7];
        uint4 r0 = tab[(s0 << 2) + j];
        uint4 r1 = tab[(s1 << 2) + j];
        uint4 r2 = tab[(s2 << 2) + j];
        uint4 r3 = tab[(s3 << 2) + j];
        uint4 r4 = tab[(s4 << 2) + j];
        uint4 r5 = tab[(s5 << 2) + j];
        uint4 r6 = tab[(s6 << 2) + j];
        uint4 r7 = tab[(s7 << 2) + j];
        acc8(r0, x); acc8(r1, y); acc8(r2, x); acc8(r3, y);
        acc8(r4, x); acc8(r5, y); acc8(r6, x); acc8(r7, y);
    }
    for (; e < e1; ++e) acc8(tab[(src_sorted[e] << 2) + j], x);
#pragma unroll
    for (int i = 0; i < 8; ++i) x[i] += y[i];

    float o[8];
#pragma unroll
    for (int i = 0; i < 8; ++i) o[i] = b[8 * j + i];
#pragma unroll
    for (int sl = 0; sl < 4; ++sl) {
#pragma unroll
        for (int r = 0; r < 8; ++r) {
            float xk = __shfl(x[r], sl, 4);
            int k = 8 * sl + r;
            float4 w0 = *reinterpret_cast<const float4*>(&Wl[k * 32 + 8 * j]);
            float4 w1 = *reinterpret_cast<const float4*>(&Wl[k * 32 + 8 * j + 4]);
            o[0] = fmaf(xk, w0.x, o[0]); o[1] = fmaf(xk, w0.y, o[1]);
            o[2] = fmaf(xk, w0.z, o[2]); o[3] = fmaf(xk, w0.w, o[3]);
            o[4] = fmaf(xk, w1.x, o[4]); o[5] = fmaf(xk, w1.y, o[5]);
            o[6] = fmaf(xk, w1.z, o[6]); o[7] = fmaf(xk, w1.w, o[7]);
        }
    }
    if (RELU) {
#pragma unroll
        for (int i = 0; i < 8; ++i) o[i] = fmaxf(o[i], 0.f);
    }
    __half2 p0 = __floats2half2_rn(o[0], o[1]);
    __half2 p1 = __floats2half2_rn(o[2], o[3]);
    __half2 p2 = __floats2half2_rn(o[4], o[5]);
    __half2 p3 = __floats2half2_rn(o[6], o[7]);
    uint4 st = make_uint4(*reinterpret_cast<unsigned*>(&p0), *reinterpret_cast<unsigned*>(&p1),
                          *reinterpret_cast<unsigned*>(&p2), *reinterpret_cast<unsigned*>(&p3));
    reinterpret_cast<uint4*>(hout)[(g << 2) + j] = st;
}

// ---- layer 4 fused: pull-agg + W3 matmul + W5 projections -> u16 (b5 folded), v16 ----
__global__ __launch_bounds__(256) void k_agg_mm_proj(const int* __restrict__ rowptr, const int* __restrict__ rowend,
                                                     const int* __restrict__ src_sorted,
                                                     const __half* __restrict__ hin, const float* __restrict__ W3,
                                                     const float* __restrict__ b3,
                                                     const float* __restrict__ W5, const float* __restrict__ b5,
                                                     __half* __restrict__ u16, __half* __restrict__ v16) {
    __shared__ float W3l[1024];
    __shared__ float W5l[2048];
    for (int i = threadIdx.x; i < 1024; i += 256) W3l[i] = W3[i];
    for (int i = threadIdx.x; i < 2048; i += 256) W5l[i] = W5[i];
    __syncthreads();
    int g = (blockIdx.x * 256 + threadIdx.x) >> 2;
    if (g >= NN) return;
    int j = threadIdx.x & 3;
    const uint4* tab = reinterpret_cast<const uint4*>(hin);
    int e0 = rowptr[g], e1 = rowend[g];
    float x[8], y[8];
#pragma unroll
    for (int i = 0; i < 8; ++i) { x[i] = 0.f; y[i] = 0.f; }
    acc8(tab[(g << 2) + j], x);  // self term
    int e = e0;
    for (; e + 8 <= e1; e += 8) {
        int s0 = src_sorted[e + 0], s1 = src_sorted[e + 1], s2 = src_sorted[e + 2], s3 = src_sorted[e + 3];
        int s4 = src_sorted[e + 4], s5 = src_sorted[e + 5], s6 = src_sorted[e + 6], s7 = src_sorted[e + 7];
        uint4 r0 = tab[(s0 << 2) + j];
        uint4 r1 = tab[(s1 << 2) + j];
        uint4 r2 = tab[(s2 << 2) + j];
        uint4 r3 = tab[(s3 << 2) + j];
        uint4 r4 = tab[(s4 << 2) + j];
        uint4 r5 = tab[(s5 << 2) + j];
        uint4 r6 = tab[(s6 << 2) + j];
        uint4 r7 = tab[(s7 << 2) + j];
        acc8(r0, x); acc8(r1, y); acc8(r2, x); acc8(r3, y);
        acc8(r4, x); acc8(r5, y); acc8(r6, x); acc8(r7, y);
    }
    for (; e < e1; ++e) acc8(tab[(src_sorted[e] << 2) + j], x);
#pragma unroll
    for (int i = 0; i < 8; ++i) x[i] += y[i];

    // x4 = agg . W3 + b3 (no relu)
    float o[8];
#pragma unroll
    for (int i = 0; i < 8; ++i) o[i] = b3[8 * j + i];
#pragma unroll
    for (int sl = 0; sl < 4; ++sl) {
#pragma unroll
        for (int r = 0; r < 8; ++r) {
            float xk = __shfl(x[r], sl, 4);
            int k = 8 * sl + r;
            float4 w0 = *reinterpret_cast<const float4*>(&W3l[k * 32 + 8 * j]);
            float4 w1 = *reinterpret_cast<const float4*>(&W3l[k * 32 + 8 * j + 4]);
            o[0] = fmaf(xk, w0.x, o[0]); o[1] = fmaf(xk, w0.y, o[1]);
            o[2] = fmaf(xk, w0.z, o[2]); o[3] = fmaf(xk, w0.w, o[3]);
            o[4] = fmaf(xk, w1.x, o[4]); o[5] = fmaf(xk, w1.y, o[5]);
            o[6] = fmaf(xk, w1.z, o[6]); o[7] = fmaf(xk, w1.w, o[7]);
        }
    }
    // u = x4 . W5[0:32,:] + b5 ; v = x4 . W5[32:64,:]
    float u[8], v[8];
#pragma unroll
    for (int i = 0; i < 8; ++i) { u[i] = b5[8 * j + i]; v[i] = 0.f; }
#pragma unroll
    for (int sl = 0; sl < 4; ++sl) {
#pragma unroll
        for (int r = 0; r < 8; ++r) {
            float xk = __shfl(o[r], sl, 4);
            int k = 8 * sl + r;
            float4 a0 = *reinterpret_cast<const float4*>(&W5l[k * 32 + 8 * j]);
            float4 a1 = *reinterpret_cast<const float4*>(&W5l[k * 32 + 8 * j + 4]);
            u[0] = fmaf(xk, a0.x, u[0]); u[1] = fmaf(xk, a0.y, u[1]);
            u[2] = fmaf(xk, a0.z, u[2]); u[3] = fmaf(xk, a0.w, u[3]);
            u[4] = fmaf(xk, a1.x, u[4]); u[5] = fmaf(xk, a1.y, u[5]);
            u[6] = fmaf(xk, a1.z, u[6]); u[7] = fmaf(xk, a1.w, u[7]);
            float4 c0 = *reinterpret_cast<const float4*>(&W5l[(32 + k) * 32 + 8 * j]);
            float4 c1 = *reinterpret_cast<const float4*>(&W5l[(32 + k) * 32 + 8 * j + 4]);
            v[0] = fmaf(xk, c0.x, v[0]); v[1] = fmaf(xk, c0.y, v[1]);
            v[2] = fmaf(xk, c0.z, v[2]); v[3] = fmaf(xk, c0.w, v[3]);
            v[4] = fmaf(xk, c1.x, v[4]); v[5] = fmaf(xk, c1.y, v[5]);
            v[6] = fmaf(xk, c1.z, v[6]); v[7] = fmaf(xk, c1.w, v[7]);
        }
    }
    __half2 pu0 = __floats2half2_rn(u[0], u[1]);
    __half2 pu1 = __floats2half2_rn(u[2], u[3]);
    __half2 pu2 = __floats2half2_rn(u[4], u[5]);
    __half2 pu3 = __floats2half2_rn(u[6], u[7]);
    uint4 su = make_uint4(*reinterpret_cast<unsigned*>(&pu0), *reinterpret_cast<unsigned*>(&pu1),
                          *reinterpret_cast<unsigned*>(&pu2), *reinterpret_cast<unsigned*>(&pu3));
    reinterpret_cast<uint4*>(u16)[(g << 2) + j] = su;
    __half2 pv0 = __floats2half2_rn(v[0], v[1]);
    __half2 pv1 = __floats2half2_rn(v[2], v[3]);
    __half2 pv2 = __floats2half2_rn(v[4], v[5]);
    __half2 pv3 = __floats2half2_rn(v[6], v[7]);
    uint4 sv = make_uint4(*reinterpret_cast<unsigned*>(&pv0), *reinterpret_cast<unsigned*>(&pv1),
                          *reinterpret_cast<unsigned*>(&pv2), *reinterpret_cast<unsigned*>(&pv3));
    reinterpret_cast<uint4*>(v16)[(g << 2) + j] = sv;
}

// ---- per-edge pd ONLY (2 edges/thread, all 16 row-loads hoisted, no LDS/sync) ----
__global__ __launch_bounds__(256) void k_edge(const int* __restrict__ src32, const int* __restrict__ dst32,
                                              const __half* __restrict__ u16, const __half* __restrict__ v16,
                                              const float* __restrict__ W6, const float* __restrict__ b6,
                                              float* __restrict__ pd_out) {
    int ea = blockIdx.x * 512 + threadIdx.x;   // EE divisible by 512
    int eb = ea + 256;
    int sa = src32[ea], da = dst32[ea];
    int sb = src32[eb], db = dst32[eb];
    const uint4* pua = reinterpret_cast<const uint4*>(u16 + ((size_t)sa << 5));
    const uint4* pva = reinterpret_cast<const uint4*>(v16 + ((size_t)da << 5));
    const uint4* pub = reinterpret_cast<const uint4*>(u16 + ((size_t)sb << 5));
    const uint4* pvb = reinterpret_cast<const uint4*>(v16 + ((size_t)db << 5));

    uint4 A[4], B[4], C[4], D[4];
#pragma unroll
    for (int q = 0; q < 4; ++q) A[q] = pua[q];
#pragma unroll
    for (int q = 0; q < 4; ++q) B[q] = pva[q];
#pragma unroll
    for (int q = 0; q < 4; ++q) C[q] = pub[q];
#pragma unroll
    for (int q = 0; q < 4; ++q) D[q] = pvb[q];
    __builtin_amdgcn_sched_barrier(0);

    float b60 = b6[0], b61 = b6[1];
    float pda0 = b60, pda1 = b61, pdb0 = b60, pdb1 = b61;
#pragma unroll
    for (int q = 0; q < 4; ++q) {
        const __half2* ah = reinterpret_cast<const __half2*>(&A[q]);
        const __half2* bh = reinterpret_cast<const __half2*>(&B[q]);
        const __half2* ch = reinterpret_cast<const __half2*>(&C[q]);
        const __half2* dh = reinterpret_cast<const __half2*>(&D[q]);
#pragma unroll
        for (int r = 0; r < 4; ++r) {
            float2 fA = __half22float2(__hadd2(ah[r], bh[r]));
            float2 fB = __half22float2(__hadd2(ch[r], dh[r]));
            int jj = q * 8 + 2 * r;
            float w00 = W6[2 * jj + 0], w01 = W6[2 * jj + 1];
            float w10 = W6[2 * (jj + 1) + 0], w11 = W6[2 * (jj + 1) + 1];
            float hA0 = fA.x >= 0.f ? fA.x : 0.1f * fA.x;
            float hA1 = fA.y >= 0.f ? fA.y : 0.1f * fA.y;
            float hB0 = fB.x >= 0.f ? fB.x : 0.1f * fB.x;
            float hB1 = fB.y >= 0.f ? fB.y : 0.1f * fB.y;
            pda0 = fmaf(hA0, w00, pda0); pda1 = fmaf(hA0, w01, pda1);
            pda0 = fmaf(hA1, w10, pda0); pda1 = fmaf(hA1, w11, pda1);
            pdb0 = fmaf(hB0, w00, pdb0); pdb1 = fmaf(hB0, w01, pdb1);
            pdb0 = fmaf(hB1, w10, pdb0); pdb1 = fmaf(hB1, w11, pdb1);
        }
    }
    reinterpret_cast<float2*>(pd_out)[ea] = make_float2(pda0, pda1);
    reinterpret_cast<float2*>(pd_out)[eb] = make_float2(pdb0, pdb1);
}

// ---- persistence image from pd (sequential re-read, register acc, grid-stride) ----
__global__ __launch_bounds__(256) void k_pimg(const float* __restrict__ pd, float* __restrict__ partial) {
    float acc[25];
#pragma unroll
    for (int i = 0; i < 25; ++i) acc[i] = 0.f;
    const float inv = 3.5355339059327378f;  // 1/(0.2*sqrt(2))

    for (int e = blockIdx.x * 256 + threadIdx.x; e < EE; e += NBI * 256) {
        float2 p = reinterpret_cast<const float2*>(pd)[e];
        float pers = p.y - p.x;
        float cb[6], cp[6];
#pragma unroll
        for (int i = 0; i < 6; ++i) {
            float te = 0.2f * (float)i;
            cb[i] = erff((te - p.x) * inv);
            cp[i] = erff((te - pers) * inv);
        }
#pragma unroll
        for (int i = 0; i < 5; ++i) {
            float pdb = 0.25f * pers * (cb[i + 1] - cb[i]);
#pragma unroll
            for (int jj = 0; jj < 5; ++jj)
                acc[i * 5 + jj] = fmaf(pdb, cp[jj + 1] - cp[jj], acc[i * 5 + jj]);
        }
    }

    int lane = threadIdx.x & 63;
    int wv = threadIdx.x >> 6;
    __shared__ float sacc[4][25];
#pragma unroll
    for (int i = 0; i < 25; ++i) {
        float v = acc[i];
        v += __shfl_down(v, 32);
        v += __shfl_down(v, 16);
        v += __shfl_down(v, 8);
        v += __shfl_down(v, 4);
        v += __shfl_down(v, 2);
        v += __shfl_down(v, 1);
        if (lane == 0) sacc[wv][i] = v;
    }
    __syncthreads();
    if (threadIdx.x < 25) {
        partial[(size_t)blockIdx.x * 25 + threadIdx.x] =
            sacc[0][threadIdx.x] + sacc[1][threadIdx.x] + sacc[2][threadIdx.x] + sacc[3][threadIdx.x];
    }
}

// ---- deterministic final reduction of block partials per bin ----
__global__ __launch_bounds__(256) void k_img(const float* __restrict__ partial, float* __restrict__ img) {
    int bin = blockIdx.x;  // 25 blocks
    float s = 0.f;
    for (int k = threadIdx.x; k < NBI; k += 256) s += partial[(size_t)k * 25 + bin];
    s += __shfl_down(s, 32);
    s += __shfl_down(s, 16);
    s += __shfl_down(s, 8);
    s += __shfl_down(s, 4);
    s += __shfl_down(s, 2);
    s += __shfl_down(s, 1);
    __shared__ float wsum[4];
    if ((threadIdx.x & 63) == 0) wsum[threadIdx.x >> 6] = s;
    __syncthreads();
    if (threadIdx.x == 0) img[bin] = wsum[0] + wsum[1] + wsum[2] + wsum[3];
}

extern "C" void kernel_launch(void* const* d_in, const int* in_sizes, int n_in,
                              void* d_out, int out_size, void* d_ws, size_t ws_size,
                              hipStream_t stream) {
    const float* x0 = (const float*)d_in[0];
    // Harness converts integer inputs to int32: edge_index0 is (2, ET) int32.
    const int* src32 = (const int*)d_in[1];
    const int* dst32 = src32 + ET;
    const float* W1 = (const float*)d_in[2];
    const float* b1 = (const float*)d_in[3];
    const float* W2 = (const float*)d_in[4];
    const float* b2 = (const float*)d_in[5];
    const float* W4 = (const float*)d_in[6];
    const float* b4 = (const float*)d_in[7];
    const float* W3 = (const float*)d_in[8];
    const float* b3 = (const float*)d_in[9];
    const float* W5 = (const float*)d_in[10];
    const float* b5 = (const float*)d_in[11];
    const float* W6 = (const float*)d_in[12];
    const float* b6 = (const float*)d_in[13];
    float* out = (float*)d_out;

    const size_t PADDED = (size_t)NBKT * CAP;        // 1,856,512
    char* w = (char*)d_ws;
    int2* pairs = (int2*)w;                          // PADDED int2
    int* src_sorted = (int*)(pairs + PADDED);        // PADDED
    int* bucket_fill = src_sorted + PADDED;          // NBKT
    int* rowptr = bucket_fill + NBKT;                // NN
    int* rowend = rowptr + NN;                       // NN
    size_t off = ((size_t)((char*)(rowend + NN) - w) + 63) & ~(size_t)63;
    __half* bufA = (__half*)(w + off);               // NN*32 halfs
    __half* bufB = bufA + (size_t)NN * 32;           // NN*32 halfs
    __half* u16 = bufB + (size_t)NN * 32;            // NN*32 halfs
    __half* v16 = u16 + (size_t)NN * 32;             // NN*32 halfs
    float* partial = (float*)(v16 + (size_t)NN * 32);// NBI*25 floats

    // ---- build CSR via padded-bucket counting sort (no count pass) ----
    k_seed<<<1, 128, 0, stream>>>(bucket_fill);
    k_bkt_scatter<<<NBLK_A, 256, 0, stream>>>(src32, dst32, bucket_fill, pairs);
    k_bkt_csr<<<NBKT, 512, 0, stream>>>(pairs, bucket_fill, rowptr, rowend, src_sorted);

    // ---- layer 1 (fused agg + expand) ----
    k_pull1<<<(NN + 255) / 256, 256, 0, stream>>>(rowptr, rowend, src_sorted, x0, W1, b1, bufA);
    // ---- layers 2-3 (4 lanes/node, uint4 gathers) ----
    k_agg_mm<1><<<(NN * 4 + 255) / 256, 256, 0, stream>>>(rowptr, rowend, src_sorted, bufA, W2, b2, bufB);
    k_agg_mm<1><<<(NN * 4 + 255) / 256, 256, 0, stream>>>(rowptr, rowend, src_sorted, bufB, W4, b4, bufA);
    // ---- layer 4 + W5 projections ----
    k_agg_mm_proj<<<(NN * 4 + 255) / 256, 256, 0, stream>>>(rowptr, rowend, src_sorted, bufA, W3, b3, W5, b5, u16, v16);

    // ---- edge MLP (pd only) ----
    k_edge<<<EE / 512, 256, 0, stream>>>(src32, dst32, u16, v16, W6, b6, out);
    // ---- persistence image from pd ----
    k_pimg<<<NBI, 256, 0, stream>>>(out, partial);
    k_img<<<25, 256, 0, stream>>>(partial, out + 2 * (size_t)EE);
}

// Round 15
// 226.464 us; speedup vs baseline: 3.6014x; 1.0587x over previous
//
#include <hip/hip_runtime.h>
#include <hip/hip_bf16.h>
#include <hip/hip_fp16.h>
#include <math.h>

#define NN 100000
#define EE 1600000
#define ET 1700000   // E + N self-loops
#define HID 32

#define BKT_SHIFT 10
#define BKT_MASK 1023
#define NBKT 98            // ceil(NN / 1024)
#define CAP 24576          // padded bucket capacity (mean padded ~20.9K + big margin)
#define EPB 4096           // edges per block in stage A
#define NBLK_A 416         // ceil(ET / EPB)
#define NBI 1024           // blocks for img kernel

// ---- seed bucket bases + zero pad-row of feature tables ----
__global__ __launch_bounds__(128) void k_seed(int* __restrict__ bucket_fill,
                                              __half* __restrict__ bufA, __half* __restrict__ bufB) {
    int t = threadIdx.x;
    if (t < NBKT) bucket_fill[t] = t * CAP;
    if (t >= 96) {  // threads 96..127 -> 32 halfs
        int i = t - 96;
        bufA[(size_t)NN * 32 + i] = __float2half(0.f);
        bufB[(size_t)NN * 32 + i] = __float2half(0.f);
    }
}

// ---- padded x0 copy (x0p[NN] = 0) ----
__global__ __launch_bounds__(256) void k_xpad(const float* __restrict__ x0, float* __restrict__ x0p) {
    int t = blockIdx.x * 256 + threadIdx.x;
    if (t < NN) x0p[t] = x0[t];
    if (t == NN) x0p[NN] = 0.f;
}

// ---- stage A: scatter packed (src<<10|dstlow) into padded bucket regions ----
__global__ __launch_bounds__(256) void k_bkt_scatter(const int* __restrict__ src32, const int* __restrict__ dst32,
                                                     int* __restrict__ bucket_fill, int* __restrict__ packed) {
    __shared__ int h[NBKT];
    __shared__ int bbase[NBKT];
    for (int i = threadIdx.x; i < NBKT; i += 256) h[i] = 0;
    __syncthreads();
    int base = blockIdx.x * EPB;
    for (int k = 0; k < EPB; k += 256) {
        int t = base + k + threadIdx.x;
        if (t < ET) atomicAdd(&h[dst32[t] >> BKT_SHIFT], 1);
    }
    __syncthreads();
    for (int i = threadIdx.x; i < NBKT; i += 256) {
        int c = h[i];
        bbase[i] = c ? atomicAdd(&bucket_fill[i], c) : 0;
        h[i] = 0;  // becomes local fill counter (same thread owns bin -> no race)
    }
    __syncthreads();
    for (int k = 0; k < EPB; k += 256) {
        int t = base + k + threadIdx.x;
        if (t < ET) {
            int sv = src32[t], dv = dst32[t];
            int b = dv >> BKT_SHIFT;
            int off = atomicAdd(&h[b], 1);
            packed[bbase[b] + off] = (sv << 10) | (dv & BKT_MASK);
        }
    }
}

// ---- stage B: per-bucket fine CSR with 8-padded segments; pad slots -> NN (zero row) ----
__global__ __launch_bounds__(512) void k_bkt_csr(const int* __restrict__ packed, const int* __restrict__ bucket_fill,
                                                 int* __restrict__ rowptr, int* __restrict__ rowend,
                                                 int* __restrict__ src_sorted) {
    __shared__ int h[1024];
    __shared__ int pend[1024];
    __shared__ int tmp[512];
    int t = threadIdx.x;
    int b = blockIdx.x;
    int e0 = b * CAP, e1 = bucket_fill[b];
    int node0 = b << BKT_SHIFT;

    h[t] = 0;
    h[t + 512] = 0;
    __syncthreads();
    for (int e = e0 + t; e < e1; e += 512) atomicAdd(&h[packed[e] & BKT_MASK], 1);
    __syncthreads();

    int i0 = 2 * t, i1 = 2 * t + 1;
    int v0 = h[i0], v1 = h[i1];
    int p0 = (v0 + 7) & ~7;   // padded counts
    int p1 = (v1 + 7) & ~7;
    int s = p0 + p1;
    tmp[t] = s;
    for (int off = 1; off < 512; off <<= 1) {
        __syncthreads();
        int u = (t >= off) ? tmp[t - off] : 0;
        __syncthreads();
        tmp[t] += u;
    }
    __syncthreads();
    int excl = tmp[t] - s;
    h[i0] = excl;            // padded segment start (fill cursor)
    h[i1] = excl + p0;
    pend[i0] = excl + p0;    // padded segment end
    pend[i1] = excl + p0 + p1;
    __syncthreads();

    int n0 = node0 + i0, n1 = node0 + i1;
    if (n0 < NN) { rowptr[n0] = e0 + h[i0]; rowend[n0] = e0 + pend[i0]; }
    if (n1 < NN) { rowptr[n1] = e0 + h[i1]; rowend[n1] = e0 + pend[i1]; }
    __syncthreads();

    for (int e = e0 + t; e < e1; e += 512) {
        int pk = packed[e];
        int sl = atomicAdd(&h[pk & BKT_MASK], 1);
        src_sorted[e0 + sl] = pk >> 10;   // src (non-negative, logical shift ok)
    }
    __syncthreads();

    // fill pad slots with NN (zero-row index)
    for (int i = t; i < 1024; i += 512) {
        if (node0 + i < NN) {
            for (int e = h[i]; e < pend[i]; ++e) src_sorted[e0 + e] = NN;
        }
    }
}

// ---- helpers ----
__device__ __forceinline__ void acc8(uint4 r, float* c) {
    float2 f0 = __half22float2(*reinterpret_cast<__half2*>(&r.x));
    float2 f1 = __half22float2(*reinterpret_cast<__half2*>(&r.y));
    float2 f2 = __half22float2(*reinterpret_cast<__half2*>(&r.z));
    float2 f3 = __half22float2(*reinterpret_cast<__half2*>(&r.w));
    c[0] += f0.x; c[1] += f0.y; c[2] += f1.x; c[3] += f1.y;
    c[4] += f2.x; c[5] += f2.y; c[6] += f3.x; c[7] += f3.y;
}

// ---- layer 1 fused: thread-per-node pull-agg (padded x0p) + 1->32 linear + relu ----
__global__ __launch_bounds__(256) void k_pull1(const int* __restrict__ rowptr, const int* __restrict__ rowend,
                                               const int* __restrict__ src_sorted,
                                               const float* __restrict__ x0p, const float* __restrict__ W1,
                                               const float* __restrict__ b1, __half* __restrict__ hout) {
    __shared__ float W1l[32], b1l[32];
    if (threadIdx.x < 32) {
        W1l[threadIdx.x] = W1[threadIdx.x];
        b1l[threadIdx.x] = b1[threadIdx.x];
    }
    __syncthreads();
    int g = blockIdx.x * 256 + threadIdx.x;
    if (g >= NN) return;
    int e0 = rowptr[g], e1 = rowend[g];   // padded, multiple of 8
    float a0 = x0p[g], a1 = 0.f, a2 = 0.f, a3 = 0.f, a4 = 0.f, a5 = 0.f, a6 = 0.f, a7 = 0.f;
    for (int e = e0; e < e1; e += 8) {
        a0 += x0p[src_sorted[e + 0]];
        a1 += x0p[src_sorted[e + 1]];
        a2 += x0p[src_sorted[e + 2]];
        a3 += x0p[src_sorted[e + 3]];
        a4 += x0p[src_sorted[e + 4]];
        a5 += x0p[src_sorted[e + 5]];
        a6 += x0p[src_sorted[e + 6]];
        a7 += x0p[src_sorted[e + 7]];
    }
    float s = ((a0 + a1) + (a2 + a3)) + ((a4 + a5) + (a6 + a7));

    uint4* orow = reinterpret_cast<uint4*>(hout) + ((size_t)g << 2);
#pragma unroll
    for (int q = 0; q < 4; ++q) {
        float o0 = fmaxf(fmaf(s, W1l[8 * q + 0], b1l[8 * q + 0]), 0.f);
        float o1 = fmaxf(fmaf(s, W1l[8 * q + 1], b1l[8 * q + 1]), 0.f);
        float o2 = fmaxf(fmaf(s, W1l[8 * q + 2], b1l[8 * q + 2]), 0.f);
        float o3 = fmaxf(fmaf(s, W1l[8 * q + 3], b1l[8 * q + 3]), 0.f);
        float o4 = fmaxf(fmaf(s, W1l[8 * q + 4], b1l[8 * q + 4]), 0.f);
        float o5 = fmaxf(fmaf(s, W1l[8 * q + 5], b1l[8 * q + 5]), 0.f);
        float o6 = fmaxf(fmaf(s, W1l[8 * q + 6], b1l[8 * q + 6]), 0.f);
        float o7 = fmaxf(fmaf(s, W1l[8 * q + 7], b1l[8 * q + 7]), 0.f);
        __half2 p0 = __floats2half2_rn(o0, o1);
        __half2 p1 = __floats2half2_rn(o2, o3);
        __half2 p2 = __floats2half2_rn(o4, o5);
        __half2 p3 = __floats2half2_rn(o6, o7);
        orow[q] = make_uint4(*reinterpret_cast<unsigned*>(&p0), *reinterpret_cast<unsigned*>(&p1),
                             *reinterpret_cast<unsigned*>(&p2), *reinterpret_cast<unsigned*>(&p3));
    }
}

// ---- gather pipeline: 2 batches of 8 uint4 loads in flight, then consume ----
#define LOAD8(RR, EBASE)                                            \
    {                                                               \
        int s0 = src_sorted[(EBASE) + 0], s1 = src_sorted[(EBASE) + 1]; \
        int s2 = src_sorted[(EBASE) + 2], s3 = src_sorted[(EBASE) + 3]; \
        int s4 = src_sorted[(EBASE) + 4], s5 = src_sorted[(EBASE) + 5]; \
        int s6 = src_sorted[(EBASE) + 6], s7 = src_sorted[(EBASE) + 7]; \
        RR[0] = tab[(s0 << 2) + j]; RR[1] = tab[(s1 << 2) + j];     \
        RR[2] = tab[(s2 << 2) + j]; RR[3] = tab[(s3 << 2) + j];     \
        RR[4] = tab[(s4 << 2) + j]; RR[5] = tab[(s5 << 2) + j];     \
        RR[6] = tab[(s6 << 2) + j]; RR[7] = tab[(s7 << 2) + j];     \
    }
#define CONS8(RR)                                                   \
    {                                                               \
        acc8(RR[0], x); acc8(RR[1], y); acc8(RR[2], x); acc8(RR[3], y); \
        acc8(RR[4], x); acc8(RR[5], y); acc8(RR[6], x); acc8(RR[7], y); \
    }

// ---- fused pull-agg + 32x32 matmul (+relu), 4 lanes/node, padded 2-batch pipeline ----
template <int RELU>
__global__ __launch_bounds__(256) void k_agg_mm(const int* __restrict__ rowptr, const int* __restrict__ rowend,
                                                const int* __restrict__ src_sorted,
                                                const __half* __restrict__ hin, const float* __restrict__ W,
                                                const float* __restrict__ b, __half* __restrict__ hout) {
    __shared__ float Wl[1024];
    for (int i = threadIdx.x; i < 1024; i += 256) Wl[i] = W[i];
    __syncthreads();
    int g = (blockIdx.x * 256 + threadIdx.x) >> 2;   // 64 nodes/block
    if (g >= NN) return;
    int j = threadIdx.x & 3;
    const uint4* tab = reinterpret_cast<const uint4*>(hin);
    int e = rowptr[g], e1 = rowend[g];   // padded length, multiple of 8, >= 8
    float x[8], y[8];
#pragma unroll
    for (int i = 0; i < 8; ++i) { x[i] = 0.f; y[i] = 0.f; }
    acc8(tab[(g << 2) + j], x);  // self term
    uint4 rA[8], rB[8];
    for (; e + 16 <= e1; e += 16) {
        LOAD8(rA, e)
        LOAD8(rB, e + 8)
        __builtin_amdgcn_sched_barrier(0);
        CONS8(rA)
        CONS8(rB)
    }
    if (e < e1) {
        LOAD8(rA, e)
        __builtin_amdgcn_sched_barrier(0);
        CONS8(rA)
    }
#pragma unroll
    for (int i = 0; i < 8; ++i) x[i] += y[i];

    float o[8];
#pragma unroll
    for (int i = 0; i < 8; ++i) o[i] = b[8 * j + i];
#pragma unroll
    for (int sl = 0; sl < 4; ++sl) {
#pragma unroll
        for (int r = 0; r < 8; ++r) {
            float xk = __shfl(x[r], sl, 4);
            int k = 8 * sl + r;
            float4 w0 = *reinterpret_cast<const float4*>(&Wl[k * 32 + 8 * j]);
            float4 w1 = *reinterpret_cast<const float4*>(&Wl[k * 32 + 8 * j + 4]);
            o[0] = fmaf(xk, w0.x, o[0]); o[1] = fmaf(xk, w0.y, o[1]);
            o[2] = fmaf(xk, w0.z, o[2]); o[3] = fmaf(xk, w0.w, o[3]);
            o[4] = fmaf(xk, w1.x, o[4]); o[5] = fmaf(xk, w1.y, o[5]);
            o[6] = fmaf(xk, w1.z, o[6]); o[7] = fmaf(xk, w1.w, o[7]);
        }
    }
    if (RELU) {
#pragma unroll
        for (int i = 0; i < 8; ++i) o[i] = fmaxf(o[i], 0.f);
    }
    __half2 p0 = __floats2half2_rn(o[0], o[1]);
    __half2 p1 = __floats2half2_rn(o[2], o[3]);
    __half2 p2 = __floats2half2_rn(o[4], o[5]);
    __half2 p3 = __floats2half2_rn(o[6], o[7]);
    uint4 st = make_uint4(*reinterpret_cast<unsigned*>(&p0), *reinterpret_cast<unsigned*>(&p1),
                          *reinterpret_cast<unsigned*>(&p2), *reinterpret_cast<unsigned*>(&p3));
    reinterpret_cast<uint4*>(hout)[(g << 2) + j] = st;
}

// ---- layer 4 fused: pull-agg + W3 matmul + W5 projections -> u16 (b5 folded), v16 ----
__global__ __launch_bounds__(256) void k_agg_mm_proj(const int* __restrict__ rowptr, const int* __restrict__ rowend,
                                                     const int* __restrict__ src_sorted,
                                                     const __half* __restrict__ hin, const float* __restrict__ W3,
                                                     const float* __restrict__ b3,
                                                     const float* __restrict__ W5, const float* __restrict__ b5,
                                                     __half* __restrict__ u16, __half* __restrict__ v16) {
    __shared__ float W3l[1024];
    __shared__ float W5l[2048];
    for (int i = threadIdx.x; i < 1024; i += 256) W3l[i] = W3[i];
    for (int i = threadIdx.x; i < 2048; i += 256) W5l[i] = W5[i];
    __syncthreads();
    int g = (blockIdx.x * 256 + threadIdx.x) >> 2;
    if (g >= NN) return;
    int j = threadIdx.x & 3;
    const uint4* tab = reinterpret_cast<const uint4*>(hin);
    int e = rowptr[g], e1 = rowend[g];
    float x[8], y[8];
#pragma unroll
    for (int i = 0; i < 8; ++i) { x[i] = 0.f; y[i] = 0.f; }
    acc8(tab[(g << 2) + j], x);  // self term
    uint4 rA[8], rB[8];
    for (; e + 16 <= e1; e += 16) {
        LOAD8(rA, e)
        LOAD8(rB, e + 8)
        __builtin_amdgcn_sched_barrier(0);
        CONS8(rA)
        CONS8(rB)
    }
    if (e < e1) {
        LOAD8(rA, e)
        __builtin_amdgcn_sched_barrier(0);
        CONS8(rA)
    }
#pragma unroll
    for (int i = 0; i < 8; ++i) x[i] += y[i];

    // x4 = agg . W3 + b3 (no relu)
    float o[8];
#pragma unroll
    for (int i = 0; i < 8; ++i) o[i] = b3[8 * j + i];
#pragma unroll
    for (int sl = 0; sl < 4; ++sl) {
#pragma unroll
        for (int r = 0; r < 8; ++r) {
            float xk = __shfl(x[r], sl, 4);
            int k = 8 * sl + r;
            float4 w0 = *reinterpret_cast<const float4*>(&W3l[k * 32 + 8 * j]);
            float4 w1 = *reinterpret_cast<const float4*>(&W3l[k * 32 + 8 * j + 4]);
            o[0] = fmaf(xk, w0.x, o[0]); o[1] = fmaf(xk, w0.y, o[1]);
            o[2] = fmaf(xk, w0.z, o[2]); o[3] = fmaf(xk, w0.w, o[3]);
            o[4] = fmaf(xk, w1.x, o[4]); o[5] = fmaf(xk, w1.y, o[5]);
            o[6] = fmaf(xk, w1.z, o[6]); o[7] = fmaf(xk, w1.w, o[7]);
        }
    }
    // u = x4 . W5[0:32,:] + b5 ; v = x4 . W5[32:64,:]
    float u[8], v[8];
#pragma unroll
    for (int i = 0; i < 8; ++i) { u[i] = b5[8 * j + i]; v[i] = 0.f; }
#pragma unroll
    for (int sl = 0; sl < 4; ++sl) {
#pragma unroll
        for (int r = 0; r < 8; ++r) {
            float xk = __shfl(o[r], sl, 4);
            int k = 8 * sl + r;
            float4 a0 = *reinterpret_cast<const float4*>(&W5l[k * 32 + 8 * j]);
            float4 a1 = *reinterpret_cast<const float4*>(&W5l[k * 32 + 8 * j + 4]);
            u[0] = fmaf(xk, a0.x, u[0]); u[1] = fmaf(xk, a0.y, u[1]);
            u[2] = fmaf(xk, a0.z, u[2]); u[3] = fmaf(xk, a0.w, u[3]);
            u[4] = fmaf(xk, a1.x, u[4]); u[5] = fmaf(xk, a1.y, u[5]);
            u[6] = fmaf(xk, a1.z, u[6]); u[7] = fmaf(xk, a1.w, u[7]);
            float4 c0 = *reinterpret_cast<const float4*>(&W5l[(32 + k) * 32 + 8 * j]);
            float4 c1 = *reinterpret_cast<const float4*>(&W5l[(32 + k) * 32 + 8 * j + 4]);
            v[0] = fmaf(xk, c0.x, v[0]); v[1] = fmaf(xk, c0.y, v[1]);
            v[2] = fmaf(xk, c0.z, v[2]); v[3] = fmaf(xk, c0.w, v[3]);
            v[4] = fmaf(xk, c1.x, v[4]); v[5] = fmaf(xk, c1.y, v[5]);
            v[6] = fmaf(xk, c1.z, v[6]); v[7] = fmaf(xk, c1.w, v[7]);
        }
    }
    __half2 pu0 = __floats2half2_rn(u[0], u[1]);
    __half2 pu1 = __floats2half2_rn(u[2], u[3]);
    __half2 pu2 = __floats2half2_rn(u[4], u[5]);
    __half2 pu3 = __floats2half2_rn(u[6], u[7]);
    uint4 su = make_uint4(*reinterpret_cast<unsigned*>(&pu0), *reinterpret_cast<unsigned*>(&pu1),
                          *reinterpret_cast<unsigned*>(&pu2), *reinterpret_cast<unsigned*>(&pu3));
    reinterpret_cast<uint4*>(u16)[(g << 2) + j] = su;
    __half2 pv0 = __floats2half2_rn(v[0], v[1]);
    __half2 pv1 = __floats2half2_rn(v[2], v[3]);
    __half2 pv2 = __floats2half2_rn(v[4], v[5]);
    __half2 pv3 = __floats2half2_rn(v[6], v[7]);
    uint4 sv = make_uint4(*reinterpret_cast<unsigned*>(&pv0), *reinterpret_cast<unsigned*>(&pv1),
                          *reinterpret_cast<unsigned*>(&pv2), *reinterpret_cast<unsigned*>(&pv3));
    reinterpret_cast<uint4*>(v16)[(g << 2) + j] = sv;
}

// ---- per-edge pd ONLY (2 edges/thread, all 16 row-loads hoisted, no LDS/sync) ----
__global__ __launch_bounds__(256) void k_edge(const int* __restrict__ src32, const int* __restrict__ dst32,
                                              const __half* __restrict__ u16, const __half* __restrict__ v16,
                                              const float* __restrict__ W6, const float* __restrict__ b6,
                                              float* __restrict__ pd_out) {
    int ea = blockIdx.x * 512 + threadIdx.x;   // EE divisible by 512
    int eb = ea + 256;
    int sa = src32[ea], da = dst32[ea];
    int sb = src32[eb], db = dst32[eb];
    const uint4* pua = reinterpret_cast<const uint4*>(u16 + ((size_t)sa << 5));
    const uint4* pva = reinterpret_cast<const uint4*>(v16 + ((size_t)da << 5));
    const uint4* pub = reinterpret_cast<const uint4*>(u16 + ((size_t)sb << 5));
    const uint4* pvb = reinterpret_cast<const uint4*>(v16 + ((size_t)db << 5));

    uint4 A[4], B[4], C[4], D[4];
#pragma unroll
    for (int q = 0; q < 4; ++q) A[q] = pua[q];
#pragma unroll
    for (int q = 0; q < 4; ++q) B[q] = pva[q];
#pragma unroll
    for (int q = 0; q < 4; ++q) C[q] = pub[q];
#pragma unroll
    for (int q = 0; q < 4; ++q) D[q] = pvb[q];
    __builtin_amdgcn_sched_barrier(0);

    float b60 = b6[0], b61 = b6[1];
    float pda0 = b60, pda1 = b61, pdb0 = b60, pdb1 = b61;
#pragma unroll
    for (int q = 0; q < 4; ++q) {
        const __half2* ah = reinterpret_cast<const __half2*>(&A[q]);
        const __half2* bh = reinterpret_cast<const __half2*>(&B[q]);
        const __half2* ch = reinterpret_cast<const __half2*>(&C[q]);
        const __half2* dh = reinterpret_cast<const __half2*>(&D[q]);
#pragma unroll
        for (int r = 0; r < 4; ++r) {
            float2 fA = __half22float2(__hadd2(ah[r], bh[r]));
            float2 fB = __half22float2(__hadd2(ch[r], dh[r]));
            int jj = q * 8 + 2 * r;
            float w00 = W6[2 * jj + 0], w01 = W6[2 * jj + 1];
            float w10 = W6[2 * (jj + 1) + 0], w11 = W6[2 * (jj + 1) + 1];
            float hA0 = fA.x >= 0.f ? fA.x : 0.1f * fA.x;
            float hA1 = fA.y >= 0.f ? fA.y : 0.1f * fA.y;
            float hB0 = fB.x >= 0.f ? fB.x : 0.1f * fB.x;
            float hB1 = fB.y >= 0.f ? fB.y : 0.1f * fB.y;
            pda0 = fmaf(hA0, w00, pda0); pda1 = fmaf(hA0, w01, pda1);
            pda0 = fmaf(hA1, w10, pda0); pda1 = fmaf(hA1, w11, pda1);
            pdb0 = fmaf(hB0, w00, pdb0); pdb1 = fmaf(hB0, w01, pdb1);
            pdb0 = fmaf(hB1, w10, pdb0); pdb1 = fmaf(hB1, w11, pdb1);
        }
    }
    reinterpret_cast<float2*>(pd_out)[ea] = make_float2(pda0, pda1);
    reinterpret_cast<float2*>(pd_out)[eb] = make_float2(pdb0, pdb1);
}

// ---- persistence image from pd (sequential re-read, register acc, grid-stride) ----
__global__ __launch_bounds__(256) void k_pimg(const float* __restrict__ pd, float* __restrict__ partial) {
    float acc[25];
#pragma unroll
    for (int i = 0; i < 25; ++i) acc[i] = 0.f;
    const float inv = 3.5355339059327378f;  // 1/(0.2*sqrt(2))

    for (int e = blockIdx.x * 256 + threadIdx.x; e < EE; e += NBI * 256) {
        float2 p = reinterpret_cast<const float2*>(pd)[e];
        float pers = p.y - p.x;
        float cb[6], cp[6];
#pragma unroll
        for (int i = 0; i < 6; ++i) {
            float te = 0.2f * (float)i;
            cb[i] = erff((te - p.x) * inv);
            cp[i] = erff((te - pers) * inv);
        }
#pragma unroll
        for (int i = 0; i < 5; ++i) {
            float pdb = 0.25f * pers * (cb[i + 1] - cb[i]);
#pragma unroll
            for (int jj = 0; jj < 5; ++jj)
                acc[i * 5 + jj] = fmaf(pdb, cp[jj + 1] - cp[jj], acc[i * 5 + jj]);
        }
    }

    int lane = threadIdx.x & 63;
    int wv = threadIdx.x >> 6;
    __shared__ float sacc[4][25];
#pragma unroll
    for (int i = 0; i < 25; ++i) {
        float v = acc[i];
        v += __shfl_down(v, 32);
        v += __shfl_down(v, 16);
        v += __shfl_down(v, 8);
        v += __shfl_down(v, 4);
        v += __shfl_down(v, 2);
        v += __shfl_down(v, 1);
        if (lane == 0) sacc[wv][i] = v;
    }
    __syncthreads();
    if (threadIdx.x < 25) {
        partial[(size_t)blockIdx.x * 25 + threadIdx.x] =
            sacc[0][threadIdx.x] + sacc[1][threadIdx.x] + sacc[2][threadIdx.x] + sacc[3][threadIdx.x];
    }
}

// ---- deterministic final reduction of block partials per bin ----
__global__ __launch_bounds__(256) void k_img(const float* __restrict__ partial, float* __restrict__ img) {
    int bin = blockIdx.x;  // 25 blocks
    float s = 0.f;
    for (int k = threadIdx.x; k < NBI; k += 256) s += partial[(size_t)k * 25 + bin];
    s += __shfl_down(s, 32);
    s += __shfl_down(s, 16);
    s += __shfl_down(s, 8);
    s += __shfl_down(s, 4);
    s += __shfl_down(s, 2);
    s += __shfl_down(s, 1);
    __shared__ float wsum[4];
    if ((threadIdx.x & 63) == 0) wsum[threadIdx.x >> 6] = s;
    __syncthreads();
    if (threadIdx.x == 0) img[bin] = wsum[0] + wsum[1] + wsum[2] + wsum[3];
}

extern "C" void kernel_launch(void* const* d_in, const int* in_sizes, int n_in,
                              void* d_out, int out_size, void* d_ws, size_t ws_size,
                              hipStream_t stream) {
    const float* x0 = (const float*)d_in[0];
    // Harness converts integer inputs to int32: edge_index0 is (2, ET) int32.
    const int* src32 = (const int*)d_in[1];
    const int* dst32 = src32 + ET;
    const float* W1 = (const float*)d_in[2];
    const float* b1 = (const float*)d_in[3];
    const float* W2 = (const float*)d_in[4];
    const float* b2 = (const float*)d_in[5];
    const float* W4 = (const float*)d_in[6];
    const float* b4 = (const float*)d_in[7];
    const float* W3 = (const float*)d_in[8];
    const float* b3 = (const float*)d_in[9];
    const float* W5 = (const float*)d_in[10];
    const float* b5 = (const float*)d_in[11];
    const float* W6 = (const float*)d_in[12];
    const float* b6 = (const float*)d_in[13];
    float* out = (float*)d_out;

    const size_t PADDED = (size_t)NBKT * CAP;        // 2,408,448
    char* w = (char*)d_ws;
    int* packed = (int*)w;                           // PADDED
    int* src_sorted = packed + PADDED;               // PADDED
    int* bucket_fill = src_sorted + PADDED;          // NBKT
    int* rowptr = bucket_fill + NBKT;                // NN
    int* rowend = rowptr + NN;                       // NN
    float* x0p = (float*)(rowend + NN);              // NN+1
    size_t off = ((size_t)((char*)(x0p + NN + 1) - w) + 63) & ~(size_t)63;
    __half* bufA = (__half*)(w + off);               // (NN+1)*32 halfs
    __half* bufB = bufA + (size_t)(NN + 1) * 32;     // (NN+1)*32 halfs
    __half* u16 = bufB + (size_t)(NN + 1) * 32;      // NN*32 halfs
    __half* v16 = u16 + (size_t)NN * 32;             // NN*32 halfs
    float* partial = (float*)(v16 + (size_t)NN * 32);// NBI*25 floats

    // ---- build padded CSR via bucket counting sort ----
    k_seed<<<1, 128, 0, stream>>>(bucket_fill, bufA, bufB);
    k_xpad<<<(NN + 256) / 256, 256, 0, stream>>>(x0, x0p);
    k_bkt_scatter<<<NBLK_A, 256, 0, stream>>>(src32, dst32, bucket_fill, packed);
    k_bkt_csr<<<NBKT, 512, 0, stream>>>(packed, bucket_fill, rowptr, rowend, src_sorted);

    // ---- layer 1 (fused agg + expand) ----
    k_pull1<<<(NN + 255) / 256, 256, 0, stream>>>(rowptr, rowend, src_sorted, x0p, W1, b1, bufA);
    // ---- layers 2-3 (4 lanes/node, padded 2-batch pipeline) ----
    k_agg_mm<1><<<(NN * 4 + 255) / 256, 256, 0, stream>>>(rowptr, rowend, src_sorted, bufA, W2, b2, bufB);
    k_agg_mm<1><<<(NN * 4 + 255) / 256, 256, 0, stream>>>(rowptr, rowend, src_sorted, bufB, W4, b4, bufA);
    // ---- layer 4 + W5 projections ----
    k_agg_mm_proj<<<(NN * 4 + 255) / 256, 256, 0, stream>>>(rowptr, rowend, src_sorted, bufA, W3, b3, W5, b5, u16, v16);

    // ---- edge MLP (pd only) ----
    k_edge<<<EE / 512, 256, 0, stream>>>(src32, dst32, u16, v16, W6, b6, out);
    // ---- persistence image from pd ----
    k_pimg<<<NBI, 256, 0, stream>>>(out, partial);
    k_img<<<25, 256, 0, stream>>>(partial, out + 2 * (size_t)EE);
}